// Round 9
// baseline (769.438 us; speedup 1.0000x reference)
//
#include <hip/hip_runtime.h>
#include <hip/hip_bf16.h>

#define NEG_SLOPE 0.01f
#define BN_EPS 1e-5f
#define POOL_S 16

typedef __attribute__((ext_vector_type(8))) short short8;
typedef __attribute__((ext_vector_type(4))) float f32x4;

__device__ __forceinline__ float bf2f(unsigned short b) {
    unsigned int u = ((unsigned int)b) << 16;
    float f; __builtin_memcpy(&f, &u, 4); return f;
}
__device__ __forceinline__ unsigned short f2bf(float f) {
    unsigned int u; __builtin_memcpy(&u, &f, 4);
    u = (u + 0x7FFFu + ((u >> 16) & 1u)) >> 16;
    return (unsigned short)u;
}

__device__ __forceinline__ void gload_lds16(const void* g, void* l) {
    __builtin_amdgcn_global_load_lds(
        (const __attribute__((address_space(1))) void*)g,
        (__attribute__((address_space(3))) void*)l, 16, 0, 0);
}

// ---------------- x fp32 -> bf16 ----------------
__global__ void k_cvt(const float* __restrict__ x, unsigned short* __restrict__ xb, int total8) {
    int i = blockIdx.x * blockDim.x + threadIdx.x;
    if (i < total8) {
        float4 a = ((const float4*)x)[i * 2];
        float4 b = ((const float4*)x)[i * 2 + 1];
        short8 o;
        o[0] = (short)f2bf(a.x); o[1] = (short)f2bf(a.y);
        o[2] = (short)f2bf(a.z); o[3] = (short)f2bf(a.w);
        o[4] = (short)f2bf(b.x); o[5] = (short)f2bf(b.y);
        o[6] = (short)f2bf(b.z); o[7] = (short)f2bf(b.w);
        ((short8*)xb)[i] = o;
    }
}

// ---------------- CSR build ----------------
__global__ void k_count(const int* __restrict__ ei, int* __restrict__ cnt, int E) {
    int e0 = (blockIdx.x * blockDim.x + threadIdx.x) * 4;
    if (e0 + 3 < E) {
        int4 d = *(const int4*)(ei + E + e0);
        atomicAdd(&cnt[d.x], 1);
        atomicAdd(&cnt[d.y], 1);
        atomicAdd(&cnt[d.z], 1);
        atomicAdd(&cnt[d.w], 1);
    } else {
        for (int e = e0; e < E; ++e) atomicAdd(&cnt[ei[E + e]], 1);
    }
}

// ---- hierarchical exclusive scan (+ dinv computed in scan1) ----
__global__ __launch_bounds__(256) void k_scan1(const int* __restrict__ cnt,
                                               int* __restrict__ bsum,
                                               float* __restrict__ dinv, int n) {
    int b = blockIdx.x;
    int t = threadIdx.x;
    int base = b * 1024 + t * 4;
    int s = 0;
    #pragma unroll
    for (int i = 0; i < 4; ++i) {
        int v = (base + i < n) ? cnt[base + i] : 0;
        if (base + i < n) dinv[base + i] = rsqrtf((float)(v + 1));
        s += v;
    }
    #pragma unroll
    for (int off = 1; off < 64; off <<= 1) s += __shfl_xor(s, off, 64);
    __shared__ int ws[4];
    if ((t & 63) == 0) ws[t >> 6] = s;
    __syncthreads();
    if (t == 0) bsum[b] = ws[0] + ws[1] + ws[2] + ws[3];
}

__global__ void k_scan2(const int* __restrict__ bsum, int* __restrict__ boff,
                        int* __restrict__ row_ptr, int nb, int n) {
    int lane = threadIdx.x;    // 64
    int v = (lane < nb) ? bsum[lane] : 0;
    int x = v;
    #pragma unroll
    for (int off = 1; off < 64; off <<= 1) {
        int t = __shfl_up(x, off, 64);
        if (lane >= off) x += t;
    }
    if (lane < nb) boff[lane] = x - v;
    if (lane == 63) row_ptr[n] = x;
}

__global__ __launch_bounds__(256) void k_scan3(const int* __restrict__ cnt,
                                               const int* __restrict__ boff,
                                               int* __restrict__ row_ptr, int n) {
    int b = blockIdx.x;
    int t = threadIdx.x;
    int lane = t & 63, w = t >> 6;
    int base = b * 1024 + t * 4;
    int v[4];
    #pragma unroll
    for (int i = 0; i < 4; ++i) v[i] = (base + i < n) ? cnt[base + i] : 0;
    int tsum = v[0] + v[1] + v[2] + v[3];
    int x = tsum;
    #pragma unroll
    for (int off = 1; off < 64; off <<= 1) {
        int tt = __shfl_up(x, off, 64);
        if (lane >= off) x += tt;
    }
    __shared__ int ws[4];
    if (lane == 63) ws[w] = x;
    __syncthreads();
    int woff = 0;
    for (int k = 0; k < 4; ++k) if (k < w) woff += ws[k];
    int excl = boff[b] + woff + x - tsum;
    #pragma unroll
    for (int i = 0; i < 4; ++i) {
        if (base + i < n) row_ptr[base + i] = excl;
        excl += v[i];
    }
}

// fill via atomicSub on the (dead) counts: pos = old-1.
__global__ void k_fill(const int* __restrict__ ei, const int* __restrict__ row_ptr,
                       int* __restrict__ cnt, int* __restrict__ eidx, int E) {
    int e0 = (blockIdx.x * blockDim.x + threadIdx.x) * 4;
    if (e0 + 3 < E) {
        int4 s = *(const int4*)(ei + e0);
        int4 d = *(const int4*)(ei + E + e0);
        int p0 = atomicSub(&cnt[d.x], 1) - 1;
        int p1 = atomicSub(&cnt[d.y], 1) - 1;
        int p2 = atomicSub(&cnt[d.z], 1) - 1;
        int p3 = atomicSub(&cnt[d.w], 1) - 1;
        eidx[row_ptr[d.x] + p0] = s.x;
        eidx[row_ptr[d.y] + p1] = s.y;
        eidx[row_ptr[d.z] + p2] = s.z;
        eidx[row_ptr[d.w] + p3] = s.w;
    } else {
        for (int e = e0; e < E; ++e) {
            int src = ei[e];
            int dst = ei[E + e];
            int pos = atomicSub(&cnt[dst], 1) - 1;
            eidx[row_ptr[dst] + pos] = src;
        }
    }
}

__global__ void k_init_affine(float* __restrict__ s, float* __restrict__ sh,
                              float* __restrict__ sums) {
    int c = threadIdx.x;
    s[c] = 1.0f;
    sh[c] = 0.0f;
    sums[c] = 0.f;
    sums[256 + c] = 0.f;
}

// ---------------- W prep ----------------
__global__ void k_prepW(const float* __restrict__ W, const float* __restrict__ scale,
                        unsigned short* __restrict__ Wt, int K, int DO) {
    int idx = blockIdx.x * blockDim.x + threadIdx.x;
    if (idx < K * DO) {
        int k = idx / DO, n = idx % DO;
        float v = W[idx];
        if (scale) v *= scale[k];
        Wt[(size_t)n * K + k] = f2bf(v);
    }
}

__global__ __launch_bounds__(256) void k_prepd(const float* __restrict__ W,
                                               const float* __restrict__ sh,
                                               float* __restrict__ d, int K, int DO) {
    int c = blockIdx.x;
    int t = threadIdx.x;
    float a = (t < K) ? sh[t] * W[(size_t)t * DO + c] : 0.f;
    #pragma unroll
    for (int off = 1; off < 64; off <<= 1) a += __shfl_xor(a, off, 64);
    __shared__ float ws[4];
    if ((t & 63) == 0) ws[t >> 6] = a;
    __syncthreads();
    if (t == 0) d[c] = ws[0] + ws[1] + ws[2] + ws[3];
}

// ---------------- wave-per-node aggregation, unroll-8, EPI fuses BN stats ----
template<int COLS, bool EPI>
__global__ __launch_bounds__(256) void k_aggw(const unsigned short* __restrict__ h,
    const float* __restrict__ s, const float* __restrict__ sh,
    const float* __restrict__ dv, const float* __restrict__ bias,
    const int* __restrict__ row_ptr, const int* __restrict__ eidx,
    const float* __restrict__ dinv, unsigned short* __restrict__ t,
    float* __restrict__ sums, int N) {
    constexpr int LPR = COLS / 8;
    constexpr int GR  = 64 / LPR;
    constexpr int SH  = (COLS == 256) ? 8 : 7;
    int n = blockIdx.x * 4 + (threadIdx.x >> 6);
    bool active = (n < N);
    int l = threadIdx.x & 63;
    int ct = l & (LPR - 1);
    int gp = l / LPR;
    const unsigned short* up = h + ct * 8;
    int b = 0, e = 0;
    float dn = 0.f;
    if (active) { b = row_ptr[n]; e = row_ptr[n + 1]; dn = dinv[n]; }
    int cnt = e - b;
    int per = (cnt + GR - 1) / GR;
    int jb = b + gp * per;
    int je = min(jb + per, e);
    float acc[8] = {};
    float ssum = 0.f;
    if (active && gp == 0) {
        short8 hv = *(const short8*)(up + ((size_t)n << SH));
        #pragma unroll
        for (int i = 0; i < 8; ++i) acc[i] += dn * bf2f((unsigned short)hv[i]);
    }
    int j = jb;
    for (; j + 8 <= je; j += 8) {
        int s0 = eidx[j],     s1 = eidx[j + 1], s2 = eidx[j + 2], s3 = eidx[j + 3];
        int s4 = eidx[j + 4], s5 = eidx[j + 5], s6 = eidx[j + 6], s7 = eidx[j + 7];
        short8 r0 = *(const short8*)(up + ((size_t)s0 << SH));
        short8 r1 = *(const short8*)(up + ((size_t)s1 << SH));
        short8 r2 = *(const short8*)(up + ((size_t)s2 << SH));
        short8 r3 = *(const short8*)(up + ((size_t)s3 << SH));
        short8 r4 = *(const short8*)(up + ((size_t)s4 << SH));
        short8 r5 = *(const short8*)(up + ((size_t)s5 << SH));
        short8 r6 = *(const short8*)(up + ((size_t)s6 << SH));
        short8 r7 = *(const short8*)(up + ((size_t)s7 << SH));
        float d0 = dinv[s0], d1 = dinv[s1], d2 = dinv[s2], d3 = dinv[s3];
        float d4 = dinv[s4], d5 = dinv[s5], d6 = dinv[s6], d7 = dinv[s7];
        ssum += ((d0 + d1) + (d2 + d3)) + ((d4 + d5) + (d6 + d7));
        #pragma unroll
        for (int i = 0; i < 8; ++i) {
            float a01 = d0 * bf2f((unsigned short)r0[i]) + d1 * bf2f((unsigned short)r1[i]);
            float a23 = d2 * bf2f((unsigned short)r2[i]) + d3 * bf2f((unsigned short)r3[i]);
            float a45 = d4 * bf2f((unsigned short)r4[i]) + d5 * bf2f((unsigned short)r5[i]);
            float a67 = d6 * bf2f((unsigned short)r6[i]) + d7 * bf2f((unsigned short)r7[i]);
            acc[i] += (a01 + a23) + (a45 + a67);
        }
    }
    for (; j + 4 <= je; j += 4) {
        int s0 = eidx[j], s1 = eidx[j + 1], s2 = eidx[j + 2], s3 = eidx[j + 3];
        float d0 = dinv[s0], d1 = dinv[s1], d2 = dinv[s2], d3 = dinv[s3];
        short8 r0 = *(const short8*)(up + ((size_t)s0 << SH));
        short8 r1 = *(const short8*)(up + ((size_t)s1 << SH));
        short8 r2 = *(const short8*)(up + ((size_t)s2 << SH));
        short8 r3 = *(const short8*)(up + ((size_t)s3 << SH));
        ssum += (d0 + d1) + (d2 + d3);
        #pragma unroll
        for (int i = 0; i < 8; ++i) {
            float a01 = d0 * bf2f((unsigned short)r0[i]) + d1 * bf2f((unsigned short)r1[i]);
            float a23 = d2 * bf2f((unsigned short)r2[i]) + d3 * bf2f((unsigned short)r3[i]);
            acc[i] += a01 + a23;
        }
    }
    for (; j < je; ++j) {
        int s0 = eidx[j];
        float d0 = dinv[s0];
        ssum += d0;
        short8 r0 = *(const short8*)(up + ((size_t)s0 << SH));
        #pragma unroll
        for (int i = 0; i < 8; ++i) acc[i] += d0 * bf2f((unsigned short)r0[i]);
    }
    #pragma unroll
    for (int mask = LPR; mask < 64; mask <<= 1) {
        #pragma unroll
        for (int i = 0; i < 8; ++i) acc[i] += __shfl_xor(acc[i], mask, 64);
        ssum += __shfl_xor(ssum, mask, 64);
    }
    __shared__ float lp1[EPI ? 128 : 1];
    __shared__ float lp2[EPI ? 128 : 1];
    if constexpr (EPI) {
        if (threadIdx.x < 128) { lp1[threadIdx.x] = 0.f; lp2[threadIdx.x] = 0.f; }
        __syncthreads();
    }
    if (active && gp == 0) {
        float ws = dn * ssum + dn * dn;
        short8 ov;
        #pragma unroll
        for (int i = 0; i < 8; ++i) {
            int col = ct * 8 + i;
            float o;
            if constexpr (EPI) {
                o = dn * acc[i] + ws * dv[col] + bias[col];
                o = o > 0.f ? o : NEG_SLOPE * o;
                atomicAdd(&lp1[col], o);
                atomicAdd(&lp2[col], o * o);
            } else {
                o = s[col] * (dn * acc[i]) + sh[col] * ws;
            }
            ov[i] = (short)f2bf(o);
        }
        *(short8*)(t + ((size_t)n << SH) + ct * 8) = ov;
    }
    if constexpr (EPI) {
        __syncthreads();
        if (threadIdx.x < 128) {
            atomicAdd(&sums[threadIdx.x], lp1[threadIdx.x]);
            atomicAdd(&sums[256 + threadIdx.x], lp2[threadIdx.x]);
        }
    }
}

// ---------------- staged MFMA GEMM (128x128 tile, BK=64, swizzled LDS) -------
template<int K, int DO, bool FUSE>
__global__ __launch_bounds__(256) void k_mfma2(
    const unsigned short* __restrict__ A, const unsigned short* __restrict__ Wt,
    const float* __restrict__ bias, unsigned short* __restrict__ H,
    float* __restrict__ sums, int M) {
    __shared__ unsigned short Asm[128 * 64];
    __shared__ unsigned short Bsm[128 * 64];
    __shared__ float ls[2][128];
    int tid = threadIdx.x;
    int l = tid & 63, w = tid >> 6;
    int wr = w & 1, wc = w >> 1;
    int rl = l & 15, kh = l >> 4;
    int Rb = blockIdx.x * 128;
    int Cb = blockIdx.y * 128;
    int srow = tid >> 3;
    int sd   = tid & 7;
    f32x4 acc[4][4] = {};
    for (int k0 = 0; k0 < K; k0 += 64) {
        #pragma unroll
        for (int i = 0; i < 4; ++i) {
            int row = i * 32 + srow;
            int ss = sd ^ (row & 7);
            int rg = Rb + row; if (rg >= M) rg = M - 1;
            gload_lds16(A + (size_t)rg * K + k0 + ss * 8,
                        (char*)Asm + i * 4096 + w * 1024);
            gload_lds16(Wt + (size_t)(Cb + row) * K + k0 + ss * 8,
                        (char*)Bsm + i * 4096 + w * 1024);
        }
        __syncthreads();
        #pragma unroll
        for (int kk = 0; kk < 2; ++kk) {
            short8 af[4], bf[4];
            #pragma unroll
            for (int mf = 0; mf < 4; ++mf) {
                int r = wr * 64 + mf * 16 + rl;
                int slot = (kk * 4 + kh) ^ (r & 7);
                af[mf] = *(const short8*)((const char*)Asm + r * 128 + slot * 16);
            }
            #pragma unroll
            for (int nf = 0; nf < 4; ++nf) {
                int c = wc * 64 + nf * 16 + rl;
                int slot = (kk * 4 + kh) ^ (c & 7);
                bf[nf] = *(const short8*)((const char*)Bsm + c * 128 + slot * 16);
            }
            #pragma unroll
            for (int mf = 0; mf < 4; ++mf)
                #pragma unroll
                for (int nf = 0; nf < 4; ++nf)
                    acc[mf][nf] = __builtin_amdgcn_mfma_f32_16x16x32_bf16(
                        af[mf], bf[nf], acc[mf][nf], 0, 0, 0);
        }
        __syncthreads();
    }
    if constexpr (FUSE) {
        for (int c = tid; c < 128; c += 256) { ls[0][c] = 0.f; ls[1][c] = 0.f; }
        __syncthreads();
    }
    #pragma unroll
    for (int nf = 0; nf < 4; ++nf) {
        int cl = wc * 64 + nf * 16 + rl;
        int col = Cb + cl;
        float bcol = FUSE ? bias[col] : 0.f;
        float p1 = 0.f, p2 = 0.f;
        #pragma unroll
        for (int mf = 0; mf < 4; ++mf) {
            #pragma unroll
            for (int r = 0; r < 4; ++r) {
                int row = Rb + wr * 64 + mf * 16 + kh * 4 + r;
                if (row < M) {
                    if constexpr (FUSE) {
                        float z = acc[mf][nf][r] + bcol;
                        z = z > 0.f ? z : NEG_SLOPE * z;
                        H[(size_t)row * DO + col] = f2bf(z);
                        p1 += z; p2 += z * z;
                    } else {
                        H[(size_t)row * DO + col] = f2bf(acc[mf][nf][r]);
                    }
                }
            }
        }
        if constexpr (FUSE) {
            atomicAdd(&ls[0][cl], p1);
            atomicAdd(&ls[1][cl], p2);
        }
    }
    if constexpr (FUSE) {
        __syncthreads();
        for (int c = tid; c < 128; c += 256) {
            atomicAdd(&sums[Cb + c], ls[0][c]);
            atomicAdd(&sums[256 + Cb + c], ls[1][c]);
        }
    }
}

// ---------------- BN finalize -> affine (re-zeroes sums) ----------------
__global__ void k_finalize(float* __restrict__ sums, const float* __restrict__ g,
                           const float* __restrict__ bt, float* __restrict__ s_out,
                           float* __restrict__ sh_out, float Nf) {
    int c = threadIdx.x;
    float mu = sums[c] / Nf;
    float var = sums[256 + c] / Nf - mu * mu;
    float rs = rsqrtf(var + BN_EPS);
    float sc = g[c] * rs;
    s_out[c] = sc;
    sh_out[c] = bt[c] - mu * sc;
    sums[c] = 0.f;
    sums[256 + c] = 0.f;
}

// ---------------- global mean pool, two-stage ----------------
__global__ void k_pool1(const unsigned short* __restrict__ h, const int* __restrict__ batch,
                        float* __restrict__ part, int N) {
    int g = blockIdx.x;
    int sidx = blockIdx.y;
    int c = threadIdx.x;
    int lo = 0, hi = N;
    while (lo < hi) { int m = (lo + hi) >> 1; if (batch[m] < g) lo = m + 1; else hi = m; }
    int start = lo; hi = N;
    while (lo < hi) { int m = (lo + hi) >> 1; if (batch[m] < g + 1) lo = m + 1; else hi = m; }
    int end = lo;
    float acc = 0.f;
    for (int r = start + sidx; r < end; r += POOL_S)
        acc += bf2f(h[(size_t)r * 128 + c]);
    part[((size_t)g * POOL_S + sidx) * 128 + c] = acc;
}

__global__ void k_pool2(const float* __restrict__ part, const int* __restrict__ batch,
                        const float* __restrict__ s, const float* __restrict__ sh,
                        float* __restrict__ out, int N) {
    int g = blockIdx.x;
    int c = threadIdx.x;
    int lo = 0, hi = N;
    while (lo < hi) { int m = (lo + hi) >> 1; if (batch[m] < g) lo = m + 1; else hi = m; }
    int start = lo; hi = N;
    while (lo < hi) { int m = (lo + hi) >> 1; if (batch[m] < g + 1) lo = m + 1; else hi = m; }
    int cnt = lo - start;
    float acc = 0.f;
    #pragma unroll
    for (int i = 0; i < POOL_S; ++i) acc += part[((size_t)g * POOL_S + i) * 128 + c];
    out[(size_t)g * 128 + c] = (cnt > 0) ? (s[c] * acc / (float)cnt + sh[c]) : 0.f;
}

// ---------------- host ----------------

static inline size_t align256(size_t x) { return (x + 255) & ~(size_t)255; }

extern "C" void kernel_launch(void* const* d_in, const int* in_sizes, int n_in,
                              void* d_out, int out_size, void* d_ws, size_t ws_size,
                              hipStream_t stream) {
    const float* x   = (const float*)d_in[0];
    const int* ei    = (const int*)d_in[1];
    const int* batch = (const int*)d_in[2];
    const float* Wp[4]  = {(const float*)d_in[3], (const float*)d_in[7],
                           (const float*)d_in[11], (const float*)d_in[15]};
    const float* bp[4]  = {(const float*)d_in[4], (const float*)d_in[8],
                           (const float*)d_in[12], (const float*)d_in[16]};
    const float* gp[4]  = {(const float*)d_in[5], (const float*)d_in[9],
                           (const float*)d_in[13], (const float*)d_in[17]};
    const float* btp[4] = {(const float*)d_in[6], (const float*)d_in[10],
                           (const float*)d_in[14], (const float*)d_in[18]};

    const int N = in_sizes[0] / 128;
    const int E = in_sizes[1] / 2;
    const int G = out_size / 128;

    char* p = (char*)d_ws;
    int* deg_cnt = (int*)p;            p += align256((size_t)N * 4);
    int* row_ptr = (int*)p;            p += align256((size_t)(N + 1) * 4);
    float* dinv = (float*)p;           p += align256((size_t)N * 4);
    int* bsum = (int*)p;               p += align256(64 * 4);
    int* boff = (int*)p;               p += align256(64 * 4);
    int* eidx = (int*)p;               p += align256((size_t)E * 4);
    float* sums = (float*)p;           p += align256(512 * 4);
    float* s_arr = (float*)p;          p += align256(5 * 256 * 4);
    float* sh_arr = (float*)p;         p += align256(5 * 256 * 4);
    float* dvec = (float*)p;           p += align256(256 * 4);
    unsigned short* Wt = (unsigned short*)p; p += align256(256 * 256 * 2);
    float* part = (float*)p;           p += align256((size_t)G * POOL_S * 128 * 4);
    unsigned short* xb = (unsigned short*)p;   p += align256((size_t)N * 128 * 2);
    unsigned short* bufA = (unsigned short*)p; p += align256((size_t)N * 256 * 2);
    unsigned short* bufB = (unsigned short*)p; p += align256((size_t)N * 256 * 2);

    k_cvt<<<(N * 128 / 8 + 255) / 256, 256, 0, stream>>>(x, xb, N * 128 / 8);

    hipMemsetAsync(deg_cnt, 0, (size_t)N * 4, stream);
    k_count<<<(E / 4 + 255) / 256, 256, 0, stream>>>(ei, deg_cnt, E);
    const int nb = (N + 1023) / 1024;
    k_scan1<<<nb, 256, 0, stream>>>(deg_cnt, bsum, dinv, N);
    k_scan2<<<1, 64, 0, stream>>>(bsum, boff, row_ptr, nb, N);
    k_scan3<<<nb, 256, 0, stream>>>(deg_cnt, boff, row_ptr, N);
    k_fill<<<(E / 4 + 255) / 256, 256, 0, stream>>>(ei, row_ptr, deg_cnt, eidx, E);
    k_init_affine<<<1, 256, 0, stream>>>(s_arr, sh_arr, sums);

    const int ablocks = (N + 3) / 4;
    const int gx = (N + 127) / 128;

    // ---- L1: agg(xb) [N,128] -> mfma 128->256 fused ----
    k_aggw<128, false><<<ablocks, 256, 0, stream>>>(xb, s_arr, sh_arr, nullptr, nullptr,
        row_ptr, eidx, dinv, bufA, nullptr, N);
    k_prepW<<<(128 * 256 + 255) / 256, 256, 0, stream>>>(Wp[0], nullptr, Wt, 128, 256);
    k_mfma2<128, 256, true><<<dim3(gx, 2), 256, 0, stream>>>(bufA, Wt, bp[0], bufB, sums, N);
    k_finalize<<<1, 256, 0, stream>>>(sums, gp[0], btp[0], s_arr + 256, sh_arr + 256, (float)N);

    // ---- L2, L3 ----
    for (int L = 1; L <= 2; ++L) {
        k_aggw<256, false><<<ablocks, 256, 0, stream>>>(bufB, s_arr + L * 256, sh_arr + L * 256,
            nullptr, nullptr, row_ptr, eidx, dinv, bufA, nullptr, N);
        k_prepW<<<(256 * 256 + 255) / 256, 256, 0, stream>>>(Wp[L], nullptr, Wt, 256, 256);
        k_mfma2<256, 256, true><<<dim3(gx, 2), 256, 0, stream>>>(bufA, Wt, bp[L], bufB, sums, N);
        k_finalize<<<1, 256, 0, stream>>>(sums, gp[L], btp[L],
                                          s_arr + (L + 1) * 256, sh_arr + (L + 1) * 256, (float)N);
    }

    // ---- L4: GEMM-first (fold s3 into W, sh3 into dvec), agg+stats fused ----
    k_prepW<<<(256 * 128 + 255) / 256, 256, 0, stream>>>(Wp[3], s_arr + 3 * 256, Wt, 256, 128);
    k_prepd<<<128, 256, 0, stream>>>(Wp[3], sh_arr + 3 * 256, dvec, 256, 128);
    k_mfma2<256, 128, false><<<dim3(gx, 1), 256, 0, stream>>>(bufB, Wt, nullptr, bufA, nullptr, N);
    k_aggw<128, true><<<ablocks, 256, 0, stream>>>(bufA, nullptr, nullptr, dvec, bp[3],
        row_ptr, eidx, dinv, bufB, sums, N);
    k_finalize<<<1, 128, 0, stream>>>(sums, gp[3], btp[3], s_arr + 4 * 256, sh_arr + 4 * 256, (float)N);

    dim3 pgrid(G, POOL_S);
    k_pool1<<<pgrid, 128, 0, stream>>>(bufB, batch, part, N);
    k_pool2<<<G, 128, 0, stream>>>(part, batch, s_arr + 4 * 256, sh_arr + 4 * 256,
                                   (float*)d_out, N);
}

// Round 10
// 517.168 us; speedup vs baseline: 1.4878x; 1.4878x over previous
//
#include <hip/hip_runtime.h>
#include <hip/hip_bf16.h>

#define NEG_SLOPE 0.01f
#define BN_EPS 1e-5f
#define POOL_S 16

typedef __attribute__((ext_vector_type(8))) short short8;
typedef __attribute__((ext_vector_type(4))) float f32x4;

__device__ __forceinline__ float bf2f(unsigned short b) {
    unsigned int u = ((unsigned int)b) << 16;
    float f; __builtin_memcpy(&f, &u, 4); return f;
}
__device__ __forceinline__ unsigned short f2bf(float f) {
    unsigned int u; __builtin_memcpy(&u, &f, 4);
    u = (u + 0x7FFFu + ((u >> 16) & 1u)) >> 16;
    return (unsigned short)u;
}

__device__ __forceinline__ void gload_lds16(const void* g, void* l) {
    __builtin_amdgcn_global_load_lds(
        (const __attribute__((address_space(1))) void*)g,
        (__attribute__((address_space(3))) void*)l, 16, 0, 0);
}

// ---------------- x fp32 -> bf16 ----------------
__global__ void k_cvt(const float* __restrict__ x, unsigned short* __restrict__ xb, int total8) {
    int i = blockIdx.x * blockDim.x + threadIdx.x;
    if (i < total8) {
        float4 a = ((const float4*)x)[i * 2];
        float4 b = ((const float4*)x)[i * 2 + 1];
        short8 o;
        o[0] = (short)f2bf(a.x); o[1] = (short)f2bf(a.y);
        o[2] = (short)f2bf(a.z); o[3] = (short)f2bf(a.w);
        o[4] = (short)f2bf(b.x); o[5] = (short)f2bf(b.y);
        o[6] = (short)f2bf(b.z); o[7] = (short)f2bf(b.w);
        ((short8*)xb)[i] = o;
    }
}

// ---------------- CSR build ----------------
__global__ void k_count(const int* __restrict__ ei, int* __restrict__ cnt, int E) {
    int e0 = (blockIdx.x * blockDim.x + threadIdx.x) * 4;
    if (e0 + 3 < E) {
        int4 d = *(const int4*)(ei + E + e0);
        atomicAdd(&cnt[d.x], 1);
        atomicAdd(&cnt[d.y], 1);
        atomicAdd(&cnt[d.z], 1);
        atomicAdd(&cnt[d.w], 1);
    } else {
        for (int e = e0; e < E; ++e) atomicAdd(&cnt[ei[E + e]], 1);
    }
}

// ---- hierarchical exclusive scan (+ dinv computed in scan1) ----
__global__ __launch_bounds__(256) void k_scan1(const int* __restrict__ cnt,
                                               int* __restrict__ bsum,
                                               float* __restrict__ dinv, int n) {
    int b = blockIdx.x;
    int t = threadIdx.x;
    int base = b * 1024 + t * 4;
    int s = 0;
    #pragma unroll
    for (int i = 0; i < 4; ++i) {
        int v = (base + i < n) ? cnt[base + i] : 0;
        if (base + i < n) dinv[base + i] = rsqrtf((float)(v + 1));
        s += v;
    }
    #pragma unroll
    for (int off = 1; off < 64; off <<= 1) s += __shfl_xor(s, off, 64);
    __shared__ int ws[4];
    if ((t & 63) == 0) ws[t >> 6] = s;
    __syncthreads();
    if (t == 0) bsum[b] = ws[0] + ws[1] + ws[2] + ws[3];
}

__global__ void k_scan2(const int* __restrict__ bsum, int* __restrict__ boff,
                        int* __restrict__ row_ptr, int nb, int n) {
    int lane = threadIdx.x;    // 64
    int v = (lane < nb) ? bsum[lane] : 0;
    int x = v;
    #pragma unroll
    for (int off = 1; off < 64; off <<= 1) {
        int t = __shfl_up(x, off, 64);
        if (lane >= off) x += t;
    }
    if (lane < nb) boff[lane] = x - v;
    if (lane == 63) row_ptr[n] = x;
}

__global__ __launch_bounds__(256) void k_scan3(const int* __restrict__ cnt,
                                               const int* __restrict__ boff,
                                               int* __restrict__ row_ptr, int n) {
    int b = blockIdx.x;
    int t = threadIdx.x;
    int lane = t & 63, w = t >> 6;
    int base = b * 1024 + t * 4;
    int v[4];
    #pragma unroll
    for (int i = 0; i < 4; ++i) v[i] = (base + i < n) ? cnt[base + i] : 0;
    int tsum = v[0] + v[1] + v[2] + v[3];
    int x = tsum;
    #pragma unroll
    for (int off = 1; off < 64; off <<= 1) {
        int tt = __shfl_up(x, off, 64);
        if (lane >= off) x += tt;
    }
    __shared__ int ws[4];
    if (lane == 63) ws[w] = x;
    __syncthreads();
    int woff = 0;
    for (int k = 0; k < 4; ++k) if (k < w) woff += ws[k];
    int excl = boff[b] + woff + x - tsum;
    #pragma unroll
    for (int i = 0; i < 4; ++i) {
        if (base + i < n) row_ptr[base + i] = excl;
        excl += v[i];
    }
}

// fill via atomicSub on the (dead) counts: pos = old-1.
__global__ void k_fill(const int* __restrict__ ei, const int* __restrict__ row_ptr,
                       int* __restrict__ cnt, int* __restrict__ eidx, int E) {
    int e0 = (blockIdx.x * blockDim.x + threadIdx.x) * 4;
    if (e0 + 3 < E) {
        int4 s = *(const int4*)(ei + e0);
        int4 d = *(const int4*)(ei + E + e0);
        int p0 = atomicSub(&cnt[d.x], 1) - 1;
        int p1 = atomicSub(&cnt[d.y], 1) - 1;
        int p2 = atomicSub(&cnt[d.z], 1) - 1;
        int p3 = atomicSub(&cnt[d.w], 1) - 1;
        eidx[row_ptr[d.x] + p0] = s.x;
        eidx[row_ptr[d.y] + p1] = s.y;
        eidx[row_ptr[d.z] + p2] = s.z;
        eidx[row_ptr[d.w] + p3] = s.w;
    } else {
        for (int e = e0; e < E; ++e) {
            int src = ei[e];
            int dst = ei[E + e];
            int pos = atomicSub(&cnt[dst], 1) - 1;
            eidx[row_ptr[dst] + pos] = src;
        }
    }
}

__global__ void k_init_affine(float* __restrict__ s, float* __restrict__ sh,
                              float* __restrict__ sums) {
    int c = threadIdx.x;
    s[c] = 1.0f;
    sh[c] = 0.0f;
    sums[c] = 0.f;
    sums[256 + c] = 0.f;
}

// ---------------- W prep ----------------
__global__ void k_prepW(const float* __restrict__ W, const float* __restrict__ scale,
                        unsigned short* __restrict__ Wt, int K, int DO) {
    int idx = blockIdx.x * blockDim.x + threadIdx.x;
    if (idx < K * DO) {
        int k = idx / DO, n = idx % DO;
        float v = W[idx];
        if (scale) v *= scale[k];
        Wt[(size_t)n * K + k] = f2bf(v);
    }
}

__global__ __launch_bounds__(256) void k_prepd(const float* __restrict__ W,
                                               const float* __restrict__ sh,
                                               float* __restrict__ d, int K, int DO) {
    int c = blockIdx.x;
    int t = threadIdx.x;
    float a = (t < K) ? sh[t] * W[(size_t)t * DO + c] : 0.f;
    #pragma unroll
    for (int off = 1; off < 64; off <<= 1) a += __shfl_xor(a, off, 64);
    __shared__ float ws[4];
    if ((t & 63) == 0) ws[t >> 6] = a;
    __syncthreads();
    if (t == 0) d[c] = ws[0] + ws[1] + ws[2] + ws[3];
}

// ---------------- wave-per-node aggregation, unroll-4, in-register wsum ----
// (R7-proven shape: VGPR 32, no LDS, early return. Do NOT deepen the unroll —
//  unroll-8 raised VGPR to 60, compiler serialized loads, 5x regression (R8).)
template<int COLS, bool EPI>
__global__ __launch_bounds__(256) void k_aggw(const unsigned short* __restrict__ h,
    const float* __restrict__ s, const float* __restrict__ sh,
    const float* __restrict__ dv, const float* __restrict__ bias,
    const int* __restrict__ row_ptr, const int* __restrict__ eidx,
    const float* __restrict__ dinv, unsigned short* __restrict__ t, int N) {
    constexpr int LPR = COLS / 8;
    constexpr int GR  = 64 / LPR;
    constexpr int SH  = (COLS == 256) ? 8 : 7;
    int n = blockIdx.x * 4 + (threadIdx.x >> 6);
    if (n >= N) return;
    int l = threadIdx.x & 63;
    int ct = l & (LPR - 1);
    int gp = l / LPR;
    const unsigned short* up = h + ct * 8;
    int b = row_ptr[n], e = row_ptr[n + 1];
    int cnt = e - b;
    int per = (cnt + GR - 1) / GR;
    int jb = b + gp * per;
    int je = min(jb + per, e);
    float dn = dinv[n];
    float acc[8] = {};
    float ssum = 0.f;
    if (gp == 0) {
        short8 hv = *(const short8*)(up + ((size_t)n << SH));
        #pragma unroll
        for (int i = 0; i < 8; ++i) acc[i] += dn * bf2f((unsigned short)hv[i]);
    }
    int j = jb;
    for (; j + 4 <= je; j += 4) {
        int s0 = eidx[j], s1 = eidx[j + 1], s2 = eidx[j + 2], s3 = eidx[j + 3];
        float d0 = dinv[s0], d1 = dinv[s1], d2 = dinv[s2], d3 = dinv[s3];
        short8 r0 = *(const short8*)(up + ((size_t)s0 << SH));
        short8 r1 = *(const short8*)(up + ((size_t)s1 << SH));
        short8 r2 = *(const short8*)(up + ((size_t)s2 << SH));
        short8 r3 = *(const short8*)(up + ((size_t)s3 << SH));
        ssum += (d0 + d1) + (d2 + d3);
        #pragma unroll
        for (int i = 0; i < 8; ++i) {
            float a01 = d0 * bf2f((unsigned short)r0[i]) + d1 * bf2f((unsigned short)r1[i]);
            float a23 = d2 * bf2f((unsigned short)r2[i]) + d3 * bf2f((unsigned short)r3[i]);
            acc[i] += a01 + a23;
        }
    }
    for (; j < je; ++j) {
        int s0 = eidx[j];
        float d0 = dinv[s0];
        ssum += d0;
        short8 r0 = *(const short8*)(up + ((size_t)s0 << SH));
        #pragma unroll
        for (int i = 0; i < 8; ++i) acc[i] += d0 * bf2f((unsigned short)r0[i]);
    }
    #pragma unroll
    for (int mask = LPR; mask < 64; mask <<= 1) {
        #pragma unroll
        for (int i = 0; i < 8; ++i) acc[i] += __shfl_xor(acc[i], mask, 64);
        ssum += __shfl_xor(ssum, mask, 64);
    }
    if (gp == 0) {
        float ws = dn * ssum + dn * dn;
        short8 ov;
        #pragma unroll
        for (int i = 0; i < 8; ++i) {
            int col = ct * 8 + i;
            float o;
            if constexpr (EPI) {
                o = dn * acc[i] + ws * dv[col] + bias[col];
                o = o > 0.f ? o : NEG_SLOPE * o;
            } else {
                o = s[col] * (dn * acc[i]) + sh[col] * ws;
            }
            ov[i] = (short)f2bf(o);
        }
        *(short8*)(t + ((size_t)n << SH) + ct * 8) = ov;
    }
}

// ---------------- staged MFMA GEMM (128x128 tile, BK=64, swizzled LDS) -------
template<int K, int DO, bool FUSE>
__global__ __launch_bounds__(256) void k_mfma2(
    const unsigned short* __restrict__ A, const unsigned short* __restrict__ Wt,
    const float* __restrict__ bias, unsigned short* __restrict__ H,
    float* __restrict__ sums, int M) {
    __shared__ unsigned short Asm[128 * 64];
    __shared__ unsigned short Bsm[128 * 64];
    __shared__ float ls[2][128];
    int tid = threadIdx.x;
    int l = tid & 63, w = tid >> 6;
    int wr = w & 1, wc = w >> 1;
    int rl = l & 15, kh = l >> 4;
    int Rb = blockIdx.x * 128;
    int Cb = blockIdx.y * 128;
    int srow = tid >> 3;
    int sd   = tid & 7;
    f32x4 acc[4][4] = {};
    for (int k0 = 0; k0 < K; k0 += 64) {
        #pragma unroll
        for (int i = 0; i < 4; ++i) {
            int row = i * 32 + srow;
            int ss = sd ^ (row & 7);
            int rg = Rb + row; if (rg >= M) rg = M - 1;
            gload_lds16(A + (size_t)rg * K + k0 + ss * 8,
                        (char*)Asm + i * 4096 + w * 1024);
            gload_lds16(Wt + (size_t)(Cb + row) * K + k0 + ss * 8,
                        (char*)Bsm + i * 4096 + w * 1024);
        }
        __syncthreads();
        #pragma unroll
        for (int kk = 0; kk < 2; ++kk) {
            short8 af[4], bf[4];
            #pragma unroll
            for (int mf = 0; mf < 4; ++mf) {
                int r = wr * 64 + mf * 16 + rl;
                int slot = (kk * 4 + kh) ^ (r & 7);
                af[mf] = *(const short8*)((const char*)Asm + r * 128 + slot * 16);
            }
            #pragma unroll
            for (int nf = 0; nf < 4; ++nf) {
                int c = wc * 64 + nf * 16 + rl;
                int slot = (kk * 4 + kh) ^ (c & 7);
                bf[nf] = *(const short8*)((const char*)Bsm + c * 128 + slot * 16);
            }
            #pragma unroll
            for (int mf = 0; mf < 4; ++mf)
                #pragma unroll
                for (int nf = 0; nf < 4; ++nf)
                    acc[mf][nf] = __builtin_amdgcn_mfma_f32_16x16x32_bf16(
                        af[mf], bf[nf], acc[mf][nf], 0, 0, 0);
        }
        __syncthreads();
    }
    if constexpr (FUSE) {
        for (int c = tid; c < 128; c += 256) { ls[0][c] = 0.f; ls[1][c] = 0.f; }
        __syncthreads();
    }
    #pragma unroll
    for (int nf = 0; nf < 4; ++nf) {
        int cl = wc * 64 + nf * 16 + rl;
        int col = Cb + cl;
        float bcol = FUSE ? bias[col] : 0.f;
        float p1 = 0.f, p2 = 0.f;
        #pragma unroll
        for (int mf = 0; mf < 4; ++mf) {
            #pragma unroll
            for (int r = 0; r < 4; ++r) {
                int row = Rb + wr * 64 + mf * 16 + kh * 4 + r;
                if (row < M) {
                    if constexpr (FUSE) {
                        float z = acc[mf][nf][r] + bcol;
                        z = z > 0.f ? z : NEG_SLOPE * z;
                        H[(size_t)row * DO + col] = f2bf(z);
                        p1 += z; p2 += z * z;
                    } else {
                        H[(size_t)row * DO + col] = f2bf(acc[mf][nf][r]);
                    }
                }
            }
        }
        if constexpr (FUSE) {
            atomicAdd(&ls[0][cl], p1);
            atomicAdd(&ls[1][cl], p2);
        }
    }
    if constexpr (FUSE) {
        __syncthreads();
        for (int c = tid; c < 128; c += 256) {
            atomicAdd(&sums[Cb + c], ls[0][c]);
            atomicAdd(&sums[256 + Cb + c], ls[1][c]);
        }
    }
}

// ---------------- BN stats over bf16 [M x 128] ----------------
__global__ void k_stats_bf(const unsigned short* __restrict__ h, float* __restrict__ sums, int M) {
    int c = threadIdx.x;
    float s1 = 0.f, s2 = 0.f;
    for (int r = blockIdx.x; r < M; r += gridDim.x) {
        float v = bf2f(h[(size_t)r * 128 + c]);
        s1 += v; s2 += v * v;
    }
    atomicAdd(&sums[c], s1);
    atomicAdd(&sums[256 + c], s2);
}

// ---------------- BN finalize -> affine (re-zeroes sums) ----------------
__global__ void k_finalize(float* __restrict__ sums, const float* __restrict__ g,
                           const float* __restrict__ bt, float* __restrict__ s_out,
                           float* __restrict__ sh_out, float Nf) {
    int c = threadIdx.x;
    float mu = sums[c] / Nf;
    float var = sums[256 + c] / Nf - mu * mu;
    float rs = rsqrtf(var + BN_EPS);
    float sc = g[c] * rs;
    s_out[c] = sc;
    sh_out[c] = bt[c] - mu * sc;
    sums[c] = 0.f;
    sums[256 + c] = 0.f;
}

// ---------------- global mean pool, two-stage ----------------
__global__ void k_pool1(const unsigned short* __restrict__ h, const int* __restrict__ batch,
                        float* __restrict__ part, int N) {
    int g = blockIdx.x;
    int sidx = blockIdx.y;
    int c = threadIdx.x;
    int lo = 0, hi = N;
    while (lo < hi) { int m = (lo + hi) >> 1; if (batch[m] < g) lo = m + 1; else hi = m; }
    int start = lo; hi = N;
    while (lo < hi) { int m = (lo + hi) >> 1; if (batch[m] < g + 1) lo = m + 1; else hi = m; }
    int end = lo;
    float acc = 0.f;
    for (int r = start + sidx; r < end; r += POOL_S)
        acc += bf2f(h[(size_t)r * 128 + c]);
    part[((size_t)g * POOL_S + sidx) * 128 + c] = acc;
}

__global__ void k_pool2(const float* __restrict__ part, const int* __restrict__ batch,
                        const float* __restrict__ s, const float* __restrict__ sh,
                        float* __restrict__ out, int N) {
    int g = blockIdx.x;
    int c = threadIdx.x;
    int lo = 0, hi = N;
    while (lo < hi) { int m = (lo + hi) >> 1; if (batch[m] < g) lo = m + 1; else hi = m; }
    int start = lo; hi = N;
    while (lo < hi) { int m = (lo + hi) >> 1; if (batch[m] < g + 1) lo = m + 1; else hi = m; }
    int cnt = lo - start;
    float acc = 0.f;
    #pragma unroll
    for (int i = 0; i < POOL_S; ++i) acc += part[((size_t)g * POOL_S + i) * 128 + c];
    out[(size_t)g * 128 + c] = (cnt > 0) ? (s[c] * acc / (float)cnt + sh[c]) : 0.f;
}

// ---------------- host ----------------

static inline size_t align256(size_t x) { return (x + 255) & ~(size_t)255; }

extern "C" void kernel_launch(void* const* d_in, const int* in_sizes, int n_in,
                              void* d_out, int out_size, void* d_ws, size_t ws_size,
                              hipStream_t stream) {
    const float* x   = (const float*)d_in[0];
    const int* ei    = (const int*)d_in[1];
    const int* batch = (const int*)d_in[2];
    const float* Wp[4]  = {(const float*)d_in[3], (const float*)d_in[7],
                           (const float*)d_in[11], (const float*)d_in[15]};
    const float* bp[4]  = {(const float*)d_in[4], (const float*)d_in[8],
                           (const float*)d_in[12], (const float*)d_in[16]};
    const float* gp[4]  = {(const float*)d_in[5], (const float*)d_in[9],
                           (const float*)d_in[13], (const float*)d_in[17]};
    const float* btp[4] = {(const float*)d_in[6], (const float*)d_in[10],
                           (const float*)d_in[14], (const float*)d_in[18]};

    const int N = in_sizes[0] / 128;
    const int E = in_sizes[1] / 2;
    const int G = out_size / 128;

    char* p = (char*)d_ws;
    int* deg_cnt = (int*)p;            p += align256((size_t)N * 4);
    int* row_ptr = (int*)p;            p += align256((size_t)(N + 1) * 4);
    float* dinv = (float*)p;           p += align256((size_t)N * 4);
    int* bsum = (int*)p;               p += align256(64 * 4);
    int* boff = (int*)p;               p += align256(64 * 4);
    int* eidx = (int*)p;               p += align256((size_t)E * 4);
    float* sums = (float*)p;           p += align256(512 * 4);
    float* s_arr = (float*)p;          p += align256(5 * 256 * 4);
    float* sh_arr = (float*)p;         p += align256(5 * 256 * 4);
    float* dvec = (float*)p;           p += align256(256 * 4);
    unsigned short* Wt = (unsigned short*)p; p += align256(256 * 256 * 2);
    float* part = (float*)p;           p += align256((size_t)G * POOL_S * 128 * 4);
    unsigned short* xb = (unsigned short*)p;   p += align256((size_t)N * 128 * 2);
    unsigned short* bufA = (unsigned short*)p; p += align256((size_t)N * 256 * 2);
    unsigned short* bufB = (unsigned short*)p; p += align256((size_t)N * 256 * 2);

    k_cvt<<<(N * 128 / 8 + 255) / 256, 256, 0, stream>>>(x, xb, N * 128 / 8);

    hipMemsetAsync(deg_cnt, 0, (size_t)N * 4, stream);
    k_count<<<(E / 4 + 255) / 256, 256, 0, stream>>>(ei, deg_cnt, E);
    const int nb = (N + 1023) / 1024;
    k_scan1<<<nb, 256, 0, stream>>>(deg_cnt, bsum, dinv, N);
    k_scan2<<<1, 64, 0, stream>>>(bsum, boff, row_ptr, nb, N);
    k_scan3<<<nb, 256, 0, stream>>>(deg_cnt, boff, row_ptr, N);
    k_fill<<<(E / 4 + 255) / 256, 256, 0, stream>>>(ei, row_ptr, deg_cnt, eidx, E);
    k_init_affine<<<1, 256, 0, stream>>>(s_arr, sh_arr, sums);

    const int ablocks = (N + 3) / 4;
    const int gx = (N + 127) / 128;

    // ---- L1: agg(xb) [N,128] -> mfma 128->256 fused ----
    k_aggw<128, false><<<ablocks, 256, 0, stream>>>(xb, s_arr, sh_arr, nullptr, nullptr,
        row_ptr, eidx, dinv, bufA, N);
    k_prepW<<<(128 * 256 + 255) / 256, 256, 0, stream>>>(Wp[0], nullptr, Wt, 128, 256);
    k_mfma2<128, 256, true><<<dim3(gx, 2), 256, 0, stream>>>(bufA, Wt, bp[0], bufB, sums, N);
    k_finalize<<<1, 256, 0, stream>>>(sums, gp[0], btp[0], s_arr + 256, sh_arr + 256, (float)N);

    // ---- L2, L3 ----
    for (int L = 1; L <= 2; ++L) {
        k_aggw<256, false><<<ablocks, 256, 0, stream>>>(bufB, s_arr + L * 256, sh_arr + L * 256,
            nullptr, nullptr, row_ptr, eidx, dinv, bufA, N);
        k_prepW<<<(256 * 256 + 255) / 256, 256, 0, stream>>>(Wp[L], nullptr, Wt, 256, 256);
        k_mfma2<256, 256, true><<<dim3(gx, 2), 256, 0, stream>>>(bufA, Wt, bp[L], bufB, sums, N);
        k_finalize<<<1, 256, 0, stream>>>(sums, gp[L], btp[L],
                                          s_arr + (L + 1) * 256, sh_arr + (L + 1) * 256, (float)N);
    }

    // ---- L4: GEMM-first (fold s3 into W, sh3 into dvec), then agg in 128 cols ----
    k_prepW<<<(256 * 128 + 255) / 256, 256, 0, stream>>>(Wp[3], s_arr + 3 * 256, Wt, 256, 128);
    k_prepd<<<128, 256, 0, stream>>>(Wp[3], sh_arr + 3 * 256, dvec, 256, 128);
    k_mfma2<256, 128, false><<<dim3(gx, 1), 256, 0, stream>>>(bufB, Wt, nullptr, bufA, nullptr, N);
    k_aggw<128, true><<<ablocks, 256, 0, stream>>>(bufA, nullptr, nullptr, dvec, bp[3],
        row_ptr, eidx, dinv, bufB, N);
    k_stats_bf<<<256, 128, 0, stream>>>(bufB, sums, N);
    k_finalize<<<1, 128, 0, stream>>>(sums, gp[3], btp[3], s_arr + 4 * 256, sh_arr + 4 * 256, (float)N);

    dim3 pgrid(G, POOL_S);
    k_pool1<<<pgrid, 128, 0, stream>>>(bufB, batch, part, N);
    k_pool2<<<G, 128, 0, stream>>>(part, batch, s_arr + 4 * 256, sh_arr + 4 * 256,
                                   (float*)d_out, N);
}

// Round 12
// 489.808 us; speedup vs baseline: 1.5709x; 1.0559x over previous
//
#include <hip/hip_runtime.h>
#include <hip/hip_bf16.h>

#define NEG_SLOPE 0.01f
#define BN_EPS 1e-5f
#define POOL_S 16

typedef __attribute__((ext_vector_type(8))) short short8;
typedef __attribute__((ext_vector_type(4))) float f32x4;

__device__ __forceinline__ float bf2f(unsigned short b) {
    unsigned int u = ((unsigned int)b) << 16;
    float f; __builtin_memcpy(&f, &u, 4); return f;
}
__device__ __forceinline__ unsigned short f2bf(float f) {
    unsigned int u; __builtin_memcpy(&u, &f, 4);
    u = (u + 0x7FFFu + ((u >> 16) & 1u)) >> 16;
    return (unsigned short)u;
}

__device__ __forceinline__ void gload_lds16(const void* g, void* l) {
    __builtin_amdgcn_global_load_lds(
        (const __attribute__((address_space(1))) void*)g,
        (__attribute__((address_space(3))) void*)l, 16, 0, 0);
}

// ---------------- x fp32 -> bf16, prescaled by dinv[n] ----------------
__global__ void k_cvt(const float* __restrict__ x, const float* __restrict__ dinv,
                      unsigned short* __restrict__ xb, int total8) {
    int i = blockIdx.x * blockDim.x + threadIdx.x;
    if (i < total8) {
        float dn = dinv[i >> 4];            // 16 groups of 8 per 128-col row
        float4 a = ((const float4*)x)[i * 2];
        float4 b = ((const float4*)x)[i * 2 + 1];
        short8 o;
        o[0] = (short)f2bf(dn * a.x); o[1] = (short)f2bf(dn * a.y);
        o[2] = (short)f2bf(dn * a.z); o[3] = (short)f2bf(dn * a.w);
        o[4] = (short)f2bf(dn * b.x); o[5] = (short)f2bf(dn * b.y);
        o[6] = (short)f2bf(dn * b.z); o[7] = (short)f2bf(dn * b.w);
        ((short8*)xb)[i] = o;
    }
}

// ---------------- CSR build (padded: each row segment 4-aligned) ----------------
__global__ void k_count(const int* __restrict__ ei, int* __restrict__ cnt, int E) {
    int e0 = (blockIdx.x * blockDim.x + threadIdx.x) * 4;
    if (e0 + 3 < E) {
        int4 d = *(const int4*)(ei + E + e0);
        atomicAdd(&cnt[d.x], 1);
        atomicAdd(&cnt[d.y], 1);
        atomicAdd(&cnt[d.z], 1);
        atomicAdd(&cnt[d.w], 1);
    } else {
        for (int e = e0; e < E; ++e) atomicAdd(&cnt[ei[E + e]], 1);
    }
}

// scan1 over PADDED counts; also writes dinv (and dinv[n]=0 sentinel)
__global__ __launch_bounds__(256) void k_scan1(const int* __restrict__ cnt,
                                               int* __restrict__ bsum,
                                               float* __restrict__ dinv, int n) {
    int b = blockIdx.x;
    int t = threadIdx.x;
    if (b == 0 && t == 0) dinv[n] = 0.f;    // sentinel zero weight
    int base = b * 1024 + t * 4;
    int s = 0;
    #pragma unroll
    for (int i = 0; i < 4; ++i) {
        if (base + i < n) {
            int v = cnt[base + i];
            dinv[base + i] = rsqrtf((float)(v + 1));
            s += (v + 3) & ~3;
        }
    }
    #pragma unroll
    for (int off = 1; off < 64; off <<= 1) s += __shfl_xor(s, off, 64);
    __shared__ int ws[4];
    if ((t & 63) == 0) ws[t >> 6] = s;
    __syncthreads();
    if (t == 0) bsum[b] = ws[0] + ws[1] + ws[2] + ws[3];
}

__global__ void k_scan2(const int* __restrict__ bsum, int* __restrict__ boff,
                        int* __restrict__ row_ptr, int nb, int n) {
    int lane = threadIdx.x;    // 64
    int v = (lane < nb) ? bsum[lane] : 0;
    int x = v;
    #pragma unroll
    for (int off = 1; off < 64; off <<= 1) {
        int t = __shfl_up(x, off, 64);
        if (lane >= off) x += t;
    }
    if (lane < nb) boff[lane] = x - v;
    if (lane == 63) row_ptr[n] = x;
}

__global__ __launch_bounds__(256) void k_scan3(const int* __restrict__ cnt,
                                               const int* __restrict__ boff,
                                               int* __restrict__ row_ptr, int n) {
    int b = blockIdx.x;
    int t = threadIdx.x;
    int lane = t & 63, w = t >> 6;
    int base = b * 1024 + t * 4;
    int v[4];
    #pragma unroll
    for (int i = 0; i < 4; ++i)
        v[i] = (base + i < n) ? ((cnt[base + i] + 3) & ~3) : 0;
    int tsum = v[0] + v[1] + v[2] + v[3];
    int x = tsum;
    #pragma unroll
    for (int off = 1; off < 64; off <<= 1) {
        int tt = __shfl_up(x, off, 64);
        if (lane >= off) x += tt;
    }
    __shared__ int ws[4];
    if (lane == 63) ws[w] = x;
    __syncthreads();
    int woff = 0;
    for (int k = 0; k < 4; ++k) if (k < w) woff += ws[k];
    int excl = boff[b] + woff + x - tsum;
    #pragma unroll
    for (int i = 0; i < 4; ++i) {
        if (base + i < n) row_ptr[base + i] = excl;
        excl += v[i];
    }
}

// fill pad slots [row+cnt, row_ptr[n+1]) with sentinel N
__global__ void k_pad(const int* __restrict__ cnt, const int* __restrict__ row_ptr,
                      int* __restrict__ eidx, int N) {
    int n = blockIdx.x * blockDim.x + threadIdx.x;
    if (n < N) {
        int s = row_ptr[n] + cnt[n];
        int e = row_ptr[n + 1];
        for (int j = s; j < e; ++j) eidx[j] = N;
    }
}

// fill via atomicSub on the (dead) counts: pos = old-1.
__global__ void k_fill(const int* __restrict__ ei, const int* __restrict__ row_ptr,
                       int* __restrict__ cnt, int* __restrict__ eidx, int E) {
    int e0 = (blockIdx.x * blockDim.x + threadIdx.x) * 4;
    if (e0 + 3 < E) {
        int4 s = *(const int4*)(ei + e0);
        int4 d = *(const int4*)(ei + E + e0);
        int p0 = atomicSub(&cnt[d.x], 1) - 1;
        int p1 = atomicSub(&cnt[d.y], 1) - 1;
        int p2 = atomicSub(&cnt[d.z], 1) - 1;
        int p3 = atomicSub(&cnt[d.w], 1) - 1;
        eidx[row_ptr[d.x] + p0] = s.x;
        eidx[row_ptr[d.y] + p1] = s.y;
        eidx[row_ptr[d.z] + p2] = s.z;
        eidx[row_ptr[d.w] + p3] = s.w;
    } else {
        for (int e = e0; e < E; ++e) {
            int src = ei[e];
            int dst = ei[E + e];
            int pos = atomicSub(&cnt[dst], 1) - 1;
            eidx[row_ptr[dst] + pos] = src;
        }
    }
}

// zero sentinel rows. NOTE the stride trap (R10 bug): gathers read row N at
// N*stride for THEIR stride. xb: 128. bufB: 256 (L2/L3 gathers). bufA: 128
// (L4 EPI gather) — but L2/L3 agg writes (256-stride, rows<N) overwrite the
// N*128 region (it aliases row N/2), so bufA@N*128 must be RE-zeroed after
// the last 256-stride producer/consumer of bufA and before the L4 gather.
__global__ void k_zero(unsigned short* __restrict__ xb, unsigned short* __restrict__ bufA,
                       unsigned short* __restrict__ bufB, int N) {
    int t = threadIdx.x;   // 256
    if (t < 128) xb[(size_t)N * 128 + t] = 0;
    if (t < 128) bufA[(size_t)N * 128 + t] = 0;
    bufB[(size_t)N * 256 + t] = 0;
}

__global__ void k_zeroA128(unsigned short* __restrict__ bufA, int N) {
    int t = threadIdx.x;   // 128
    bufA[(size_t)N * 128 + t] = 0;
}

// S[n] = sum_e dinv[src]  (layer-invariant; pads hit dinv[N]=0)
__global__ __launch_bounds__(256) void k_ssum(const int* __restrict__ row_ptr,
                                              const int* __restrict__ eidx,
                                              const float* __restrict__ dinv,
                                              float* __restrict__ S, int N) {
    int n = blockIdx.x * 4 + (threadIdx.x >> 6);
    if (n >= N) return;
    int l = threadIdx.x & 63;
    int b = row_ptr[n], e = row_ptr[n + 1];
    float s = 0.f;
    for (int j = b + l * 4; j < e; j += 256) {
        int4 sv = *(const int4*)(eidx + j);
        s += (dinv[sv.x] + dinv[sv.y]) + (dinv[sv.z] + dinv[sv.w]);
    }
    #pragma unroll
    for (int off = 1; off < 64; off <<= 1) s += __shfl_xor(s, off, 64);
    if (l == 0) S[n] = s;
}

__global__ void k_init_affine(float* __restrict__ s, float* __restrict__ sh,
                              float* __restrict__ sums) {
    int c = threadIdx.x;
    s[c] = 1.0f;
    sh[c] = 0.0f;
    sums[c] = 0.f;
    sums[256 + c] = 0.f;
}

// ---------------- W prep ----------------
__global__ void k_prepW(const float* __restrict__ W, const float* __restrict__ scale,
                        unsigned short* __restrict__ Wt, int K, int DO) {
    int idx = blockIdx.x * blockDim.x + threadIdx.x;
    if (idx < K * DO) {
        int k = idx / DO, n = idx % DO;
        float v = W[idx];
        if (scale) v *= scale[k];
        Wt[(size_t)n * K + k] = f2bf(v);
    }
}

__global__ __launch_bounds__(256) void k_prepd(const float* __restrict__ W,
                                               const float* __restrict__ sh,
                                               float* __restrict__ d, int K, int DO) {
    int c = blockIdx.x;
    int t = threadIdx.x;
    float a = (t < K) ? sh[t] * W[(size_t)t * DO + c] : 0.f;
    #pragma unroll
    for (int off = 1; off < 64; off <<= 1) a += __shfl_xor(a, off, 64);
    __shared__ float ws[4];
    if ((t & 63) == 0) ws[t >> 6] = a;
    __syncthreads();
    if (t == 0) d[c] = ws[0] + ws[1] + ws[2] + ws[3];
}

// ---------------- wave-per-node aggregation: PURE SUM over prescaled rows ----
// Input rows are h_hat = dinv*h. conv = dn*(sum_e h_hat[src] + h_hat[n]); ws = dn*S[n]+dn^2
// non-EPI: o = s[c]*conv + sh[c]*ws       EPI: o = leaky(conv + ws*dv[c] + bias[c])
// (R8 lesson: keep VGPR <= ~40; unroll depth 4 only.)
template<int COLS, bool EPI>
__global__ __launch_bounds__(256) void k_aggw(const unsigned short* __restrict__ h,
    const float* __restrict__ s, const float* __restrict__ sh,
    const float* __restrict__ dv, const float* __restrict__ bias,
    const int* __restrict__ row_ptr, const int* __restrict__ eidx,
    const float* __restrict__ dinv, const float* __restrict__ S,
    unsigned short* __restrict__ t, int N) {
    constexpr int LPR = COLS / 8;
    constexpr int GR  = 64 / LPR;
    constexpr int SH  = (COLS == 256) ? 8 : 7;
    int n = blockIdx.x * 4 + (threadIdx.x >> 6);
    if (n >= N) return;
    int l = threadIdx.x & 63;
    int ct = l & (LPR - 1);
    int gp = l / LPR;
    const unsigned short* up = h + ct * 8;
    int b = row_ptr[n], e = row_ptr[n + 1];
    int cnt4 = e - b;                       // multiple of 4
    int per = (((cnt4 + GR - 1) / GR) + 3) & ~3;
    int jb = b + gp * per;
    int je = min(jb + per, e);
    float acc[8] = {};
    if (gp == 0) {                          // self term, weight 1 (already prescaled)
        short8 hv = *(const short8*)(up + ((size_t)n << SH));
        #pragma unroll
        for (int i = 0; i < 8; ++i) acc[i] += bf2f((unsigned short)hv[i]);
    }
    for (int j = jb; j < je; j += 4) {
        int4 sv = *(const int4*)(eidx + j);
        short8 r0 = *(const short8*)(up + ((size_t)sv.x << SH));
        short8 r1 = *(const short8*)(up + ((size_t)sv.y << SH));
        short8 r2 = *(const short8*)(up + ((size_t)sv.z << SH));
        short8 r3 = *(const short8*)(up + ((size_t)sv.w << SH));
        #pragma unroll
        for (int i = 0; i < 8; ++i) {
            float a01 = bf2f((unsigned short)r0[i]) + bf2f((unsigned short)r1[i]);
            float a23 = bf2f((unsigned short)r2[i]) + bf2f((unsigned short)r3[i]);
            acc[i] += a01 + a23;
        }
    }
    #pragma unroll
    for (int mask = LPR; mask < 64; mask <<= 1) {
        #pragma unroll
        for (int i = 0; i < 8; ++i) acc[i] += __shfl_xor(acc[i], mask, 64);
    }
    if (gp == 0) {
        float dn = dinv[n];
        float ws = dn * S[n] + dn * dn;
        short8 ov;
        #pragma unroll
        for (int i = 0; i < 8; ++i) {
            int col = ct * 8 + i;
            float o;
            if constexpr (EPI) {
                o = dn * acc[i] + ws * dv[col] + bias[col];
                o = o > 0.f ? o : NEG_SLOPE * o;
            } else {
                o = s[col] * (dn * acc[i]) + sh[col] * ws;
            }
            ov[i] = (short)f2bf(o);
        }
        *(short8*)(t + ((size_t)n << SH) + ct * 8) = ov;
    }
}

// ---------------- staged MFMA GEMM (128x128 tile, BK=64, swizzled LDS) -------
// FUSE: bias+leaky+BN-partials, store h_hat = bf16(dinv[row]*z) for next gather.
// !FUSE: store raw acc (L4: input already prescaled -> output is z_hat).
template<int K, int DO, bool FUSE>
__global__ __launch_bounds__(256) void k_mfma2(
    const unsigned short* __restrict__ A, const unsigned short* __restrict__ Wt,
    const float* __restrict__ bias, const float* __restrict__ dinv,
    unsigned short* __restrict__ H, float* __restrict__ sums, int M) {
    __shared__ unsigned short Asm[128 * 64];
    __shared__ unsigned short Bsm[128 * 64];
    __shared__ float ls[2][128];
    int tid = threadIdx.x;
    int l = tid & 63, w = tid >> 6;
    int wr = w & 1, wc = w >> 1;
    int rl = l & 15, kh = l >> 4;
    int Rb = blockIdx.x * 128;
    int Cb = blockIdx.y * 128;
    int srow = tid >> 3;
    int sd   = tid & 7;
    f32x4 acc[4][4] = {};
    for (int k0 = 0; k0 < K; k0 += 64) {
        #pragma unroll
        for (int i = 0; i < 4; ++i) {
            int row = i * 32 + srow;
            int ss = sd ^ (row & 7);
            int rg = Rb + row; if (rg >= M) rg = M - 1;
            gload_lds16(A + (size_t)rg * K + k0 + ss * 8,
                        (char*)Asm + i * 4096 + w * 1024);
            gload_lds16(Wt + (size_t)(Cb + row) * K + k0 + ss * 8,
                        (char*)Bsm + i * 4096 + w * 1024);
        }
        __syncthreads();
        #pragma unroll
        for (int kk = 0; kk < 2; ++kk) {
            short8 af[4], bf[4];
            #pragma unroll
            for (int mf = 0; mf < 4; ++mf) {
                int r = wr * 64 + mf * 16 + rl;
                int slot = (kk * 4 + kh) ^ (r & 7);
                af[mf] = *(const short8*)((const char*)Asm + r * 128 + slot * 16);
            }
            #pragma unroll
            for (int nf = 0; nf < 4; ++nf) {
                int c = wc * 64 + nf * 16 + rl;
                int slot = (kk * 4 + kh) ^ (c & 7);
                bf[nf] = *(const short8*)((const char*)Bsm + c * 128 + slot * 16);
            }
            #pragma unroll
            for (int mf = 0; mf < 4; ++mf)
                #pragma unroll
                for (int nf = 0; nf < 4; ++nf)
                    acc[mf][nf] = __builtin_amdgcn_mfma_f32_16x16x32_bf16(
                        af[mf], bf[nf], acc[mf][nf], 0, 0, 0);
        }
        __syncthreads();
    }
    if constexpr (FUSE) {
        for (int c = tid; c < 128; c += 256) { ls[0][c] = 0.f; ls[1][c] = 0.f; }
        __syncthreads();
        float p1[4] = {}, p2[4] = {};
        #pragma unroll
        for (int mf = 0; mf < 4; ++mf) {
            #pragma unroll
            for (int r = 0; r < 4; ++r) {
                int row = Rb + wr * 64 + mf * 16 + kh * 4 + r;
                if (row < M) {
                    float dr = dinv[row];
                    #pragma unroll
                    for (int nf = 0; nf < 4; ++nf) {
                        int col = Cb + wc * 64 + nf * 16 + rl;
                        float z = acc[mf][nf][r] + bias[col];
                        z = z > 0.f ? z : NEG_SLOPE * z;
                        H[(size_t)row * DO + col] = f2bf(dr * z);
                        p1[nf] += z; p2[nf] += z * z;
                    }
                }
            }
        }
        #pragma unroll
        for (int nf = 0; nf < 4; ++nf) {
            int cl = wc * 64 + nf * 16 + rl;
            atomicAdd(&ls[0][cl], p1[nf]);
            atomicAdd(&ls[1][cl], p2[nf]);
        }
        __syncthreads();
        for (int c = tid; c < 128; c += 256) {
            atomicAdd(&sums[Cb + c], ls[0][c]);
            atomicAdd(&sums[256 + Cb + c], ls[1][c]);
        }
    } else {
        #pragma unroll
        for (int nf = 0; nf < 4; ++nf) {
            int col = Cb + wc * 64 + nf * 16 + rl;
            #pragma unroll
            for (int mf = 0; mf < 4; ++mf) {
                #pragma unroll
                for (int r = 0; r < 4; ++r) {
                    int row = Rb + wr * 64 + mf * 16 + kh * 4 + r;
                    if (row < M) H[(size_t)row * DO + col] = f2bf(acc[mf][nf][r]);
                }
            }
        }
    }
}

// ---------------- BN finalize -> affine (re-zeroes sums) ----------------
__global__ void k_finalize(float* __restrict__ sums, const float* __restrict__ g,
                           const float* __restrict__ bt, float* __restrict__ s_out,
                           float* __restrict__ sh_out, float Nf) {
    int c = threadIdx.x;
    float mu = sums[c] / Nf;
    float var = sums[256 + c] / Nf - mu * mu;
    float rs = rsqrtf(var + BN_EPS);
    float sc = g[c] * rs;
    s_out[c] = sc;
    sh_out[c] = bt[c] - mu * sc;
    sums[c] = 0.f;
    sums[256 + c] = 0.f;
}

// ---------------- global mean pool, two-stage; pool1 fuses L4 BN stats ------
__global__ void k_pool1(const unsigned short* __restrict__ h, const int* __restrict__ batch,
                        float* __restrict__ part, float* __restrict__ sums, int N) {
    int g = blockIdx.x;
    int sidx = blockIdx.y;
    int c = threadIdx.x;   // 128
    int lo = 0, hi = N;
    while (lo < hi) { int m = (lo + hi) >> 1; if (batch[m] < g) lo = m + 1; else hi = m; }
    int start = lo; hi = N;
    while (lo < hi) { int m = (lo + hi) >> 1; if (batch[m] < g + 1) lo = m + 1; else hi = m; }
    int end = lo;
    float acc = 0.f, sq = 0.f;
    for (int r = start + sidx; r < end; r += POOL_S) {
        float v = bf2f(h[(size_t)r * 128 + c]);
        acc += v; sq += v * v;
    }
    part[((size_t)g * POOL_S + sidx) * 128 + c] = acc;
    atomicAdd(&sums[c], acc);
    atomicAdd(&sums[256 + c], sq);
}

__global__ void k_pool2(const float* __restrict__ part, const int* __restrict__ batch,
                        const float* __restrict__ s, const float* __restrict__ sh,
                        float* __restrict__ out, int N) {
    int g = blockIdx.x;
    int c = threadIdx.x;
    int lo = 0, hi = N;
    while (lo < hi) { int m = (lo + hi) >> 1; if (batch[m] < g) lo = m + 1; else hi = m; }
    int start = lo; hi = N;
    while (lo < hi) { int m = (lo + hi) >> 1; if (batch[m] < g + 1) lo = m + 1; else hi = m; }
    int cnt = lo - start;
    float acc = 0.f;
    #pragma unroll
    for (int i = 0; i < POOL_S; ++i) acc += part[((size_t)g * POOL_S + i) * 128 + c];
    out[(size_t)g * 128 + c] = (cnt > 0) ? (s[c] * acc / (float)cnt + sh[c]) : 0.f;
}

// ---------------- host ----------------

static inline size_t align256(size_t x) { return (x + 255) & ~(size_t)255; }

extern "C" void kernel_launch(void* const* d_in, const int* in_sizes, int n_in,
                              void* d_out, int out_size, void* d_ws, size_t ws_size,
                              hipStream_t stream) {
    const float* x   = (const float*)d_in[0];
    const int* ei    = (const int*)d_in[1];
    const int* batch = (const int*)d_in[2];
    const float* Wp[4]  = {(const float*)d_in[3], (const float*)d_in[7],
                           (const float*)d_in[11], (const float*)d_in[15]};
    const float* bp[4]  = {(const float*)d_in[4], (const float*)d_in[8],
                           (const float*)d_in[12], (const float*)d_in[16]};
    const float* gp[4]  = {(const float*)d_in[5], (const float*)d_in[9],
                           (const float*)d_in[13], (const float*)d_in[17]};
    const float* btp[4] = {(const float*)d_in[6], (const float*)d_in[10],
                           (const float*)d_in[14], (const float*)d_in[18]};

    const int N = in_sizes[0] / 128;
    const int E = in_sizes[1] / 2;
    const int G = out_size / 128;

    char* p = (char*)d_ws;
    int* deg_cnt = (int*)p;            p += align256((size_t)N * 4);
    int* row_ptr = (int*)p;            p += align256((size_t)(N + 1) * 4);
    float* dinv = (float*)p;           p += align256((size_t)(N + 1) * 4);
    float* Svec = (float*)p;           p += align256((size_t)N * 4);
    int* bsum = (int*)p;               p += align256(64 * 4);
    int* boff = (int*)p;               p += align256(64 * 4);
    int* eidx = (int*)p;               p += align256((size_t)(E + 3 * (N + 1)) * 4);
    float* sums = (float*)p;           p += align256(512 * 4);
    float* s_arr = (float*)p;          p += align256(5 * 256 * 4);
    float* sh_arr = (float*)p;         p += align256(5 * 256 * 4);
    float* dvec = (float*)p;           p += align256(256 * 4);
    unsigned short* Wt = (unsigned short*)p; p += align256(256 * 256 * 2);
    float* part = (float*)p;           p += align256((size_t)G * POOL_S * 128 * 4);
    unsigned short* xb = (unsigned short*)p;   p += align256((size_t)(N + 1) * 128 * 2);
    unsigned short* bufA = (unsigned short*)p; p += align256((size_t)(N + 1) * 256 * 2);
    unsigned short* bufB = (unsigned short*)p; p += align256((size_t)(N + 1) * 256 * 2);

    // ---- CSR (padded) + invariants ----
    hipMemsetAsync(deg_cnt, 0, (size_t)N * 4, stream);
    k_count<<<(E / 4 + 255) / 256, 256, 0, stream>>>(ei, deg_cnt, E);
    const int nb = (N + 1023) / 1024;
    k_scan1<<<nb, 256, 0, stream>>>(deg_cnt, bsum, dinv, N);
    k_scan2<<<1, 64, 0, stream>>>(bsum, boff, row_ptr, nb, N);
    k_scan3<<<nb, 256, 0, stream>>>(deg_cnt, boff, row_ptr, N);
    k_pad<<<(N + 255) / 256, 256, 0, stream>>>(deg_cnt, row_ptr, eidx, N);
    k_fill<<<(E / 4 + 255) / 256, 256, 0, stream>>>(ei, row_ptr, deg_cnt, eidx, E);
    k_zero<<<1, 256, 0, stream>>>(xb, bufA, bufB, N);
    k_ssum<<<(N + 3) / 4, 256, 0, stream>>>(row_ptr, eidx, dinv, Svec, N);
    k_cvt<<<(N * 128 / 8 + 255) / 256, 256, 0, stream>>>(x, dinv, xb, N * 128 / 8);
    k_init_affine<<<1, 256, 0, stream>>>(s_arr, sh_arr, sums);

    const int ablocks = (N + 3) / 4;
    const int gx = (N + 127) / 128;

    // ---- L1: agg(xb_hat) [N,128] -> mfma 128->256 fused (writes h1_hat) ----
    k_aggw<128, false><<<ablocks, 256, 0, stream>>>(xb, s_arr, sh_arr, nullptr, nullptr,
        row_ptr, eidx, dinv, Svec, bufA, N);
    k_prepW<<<(128 * 256 + 255) / 256, 256, 0, stream>>>(Wp[0], nullptr, Wt, 128, 256);
    k_mfma2<128, 256, true><<<dim3(gx, 2), 256, 0, stream>>>(bufA, Wt, bp[0], dinv, bufB, sums, N);
    k_finalize<<<1, 256, 0, stream>>>(sums, gp[0], btp[0], s_arr + 256, sh_arr + 256, (float)N);

    // ---- L2, L3 ----
    for (int L = 1; L <= 2; ++L) {
        k_aggw<256, false><<<ablocks, 256, 0, stream>>>(bufB, s_arr + L * 256, sh_arr + L * 256,
            nullptr, nullptr, row_ptr, eidx, dinv, Svec, bufA, N);
        k_prepW<<<(256 * 256 + 255) / 256, 256, 0, stream>>>(Wp[L], nullptr, Wt, 256, 256);
        k_mfma2<256, 256, true><<<dim3(gx, 2), 256, 0, stream>>>(bufA, Wt, bp[L], dinv, bufB, sums, N);
        k_finalize<<<1, 256, 0, stream>>>(sums, gp[L], btp[L],
                                          s_arr + (L + 1) * 256, sh_arr + (L + 1) * 256, (float)N);
    }

    // ---- R10 BUG FIX: restore bufA's 128-stride sentinel row (clobbered by
    // L2/L3's 256-stride agg writes) now that L3's GEMM has consumed bufA. ----
    k_zeroA128<<<1, 128, 0, stream>>>(bufA, N);

    // ---- L4: GEMM-first on h3_hat (row scale commutes) -> z_hat; agg; pool ----
    k_prepW<<<(256 * 128 + 255) / 256, 256, 0, stream>>>(Wp[3], s_arr + 3 * 256, Wt, 256, 128);
    k_prepd<<<128, 256, 0, stream>>>(Wp[3], sh_arr + 3 * 256, dvec, 256, 128);
    k_mfma2<256, 128, false><<<dim3(gx, 1), 256, 0, stream>>>(bufB, Wt, nullptr, dinv, bufA, nullptr, N);
    k_aggw<128, true><<<ablocks, 256, 0, stream>>>(bufA, nullptr, nullptr, dvec, bp[3],
        row_ptr, eidx, dinv, Svec, bufB, N);
    dim3 pgrid(G, POOL_S);
    k_pool1<<<pgrid, 128, 0, stream>>>(bufB, batch, part, sums, N);
    k_finalize<<<1, 128, 0, stream>>>(sums, gp[3], btp[3], s_arr + 4 * 256, sh_arr + 4 * 256, (float)N);
    k_pool2<<<G, 128, 0, stream>>>(part, batch, s_arr + 4 * 256, sh_arr + 4 * 256,
                                   (float*)d_out, N);
}

// Round 13
// 450.045 us; speedup vs baseline: 1.7097x; 1.0884x over previous
//
#include <hip/hip_runtime.h>
#include <hip/hip_bf16.h>

#define NEG_SLOPE 0.01f
#define BN_EPS 1e-5f
#define POOL_S 16

typedef __attribute__((ext_vector_type(8))) short short8;
typedef __attribute__((ext_vector_type(4))) float f32x4;

__device__ __forceinline__ float bf2f(unsigned short b) {
    unsigned int u = ((unsigned int)b) << 16;
    float f; __builtin_memcpy(&f, &u, 4); return f;
}
__device__ __forceinline__ unsigned short f2bf(float f) {
    unsigned int u; __builtin_memcpy(&u, &f, 4);
    u = (u + 0x7FFFu + ((u >> 16) & 1u)) >> 16;
    return (unsigned short)u;
}

__device__ __forceinline__ void gload_lds16(const void* g, void* l) {
    __builtin_amdgcn_global_load_lds(
        (const __attribute__((address_space(1))) void*)g,
        (__attribute__((address_space(3))) void*)l, 16, 0, 0);
}

// ---------------- x fp32 -> bf16, prescaled by dinv[n] ----------------
__global__ void k_cvt(const float* __restrict__ x, const float* __restrict__ dinv,
                      unsigned short* __restrict__ xb, int total8) {
    int i = blockIdx.x * blockDim.x + threadIdx.x;
    if (i < total8) {
        float dn = dinv[i >> 4];            // 16 groups of 8 per 128-col row
        float4 a = ((const float4*)x)[i * 2];
        float4 b = ((const float4*)x)[i * 2 + 1];
        short8 o;
        o[0] = (short)f2bf(dn * a.x); o[1] = (short)f2bf(dn * a.y);
        o[2] = (short)f2bf(dn * a.z); o[3] = (short)f2bf(dn * a.w);
        o[4] = (short)f2bf(dn * b.x); o[5] = (short)f2bf(dn * b.y);
        o[6] = (short)f2bf(dn * b.z); o[7] = (short)f2bf(dn * b.w);
        ((short8*)xb)[i] = o;
    }
}

// ---------------- CSR build ----------------
// k_count: counts AND records each edge's rank among its dst's edges (perm).
// This is the ONLY atomic pass; k_fill becomes atomic-free (R12 change).
__global__ void k_count(const int* __restrict__ ei, int* __restrict__ cnt,
                        int* __restrict__ perm, int E) {
    int e0 = (blockIdx.x * blockDim.x + threadIdx.x) * 4;
    if (e0 + 3 < E) {
        int4 d = *(const int4*)(ei + E + e0);
        int4 pv;
        pv.x = atomicAdd(&cnt[d.x], 1);
        pv.y = atomicAdd(&cnt[d.y], 1);
        pv.z = atomicAdd(&cnt[d.z], 1);
        pv.w = atomicAdd(&cnt[d.w], 1);
        *(int4*)(perm + e0) = pv;
    } else {
        for (int e = e0; e < E; ++e) perm[e] = atomicAdd(&cnt[ei[E + e]], 1);
    }
}

// scan1 over PADDED counts; also writes dinv (and dinv[n]=0 sentinel)
__global__ __launch_bounds__(256) void k_scan1(const int* __restrict__ cnt,
                                               int* __restrict__ bsum,
                                               float* __restrict__ dinv, int n) {
    int b = blockIdx.x;
    int t = threadIdx.x;
    if (b == 0 && t == 0) dinv[n] = 0.f;    // sentinel zero weight
    int base = b * 1024 + t * 4;
    int s = 0;
    #pragma unroll
    for (int i = 0; i < 4; ++i) {
        if (base + i < n) {
            int v = cnt[base + i];
            dinv[base + i] = rsqrtf((float)(v + 1));
            s += (v + 3) & ~3;
        }
    }
    #pragma unroll
    for (int off = 1; off < 64; off <<= 1) s += __shfl_xor(s, off, 64);
    __shared__ int ws[4];
    if ((t & 63) == 0) ws[t >> 6] = s;
    __syncthreads();
    if (t == 0) bsum[b] = ws[0] + ws[1] + ws[2] + ws[3];
}

__global__ void k_scan2(const int* __restrict__ bsum, int* __restrict__ boff,
                        int* __restrict__ row_ptr, int nb, int n) {
    int lane = threadIdx.x;    // 64
    int v = (lane < nb) ? bsum[lane] : 0;
    int x = v;
    #pragma unroll
    for (int off = 1; off < 64; off <<= 1) {
        int t = __shfl_up(x, off, 64);
        if (lane >= off) x += t;
    }
    if (lane < nb) boff[lane] = x - v;
    if (lane == 63) row_ptr[n] = x;
}

// scan3: writes row_ptr AND the pad sentinels (merged k_pad, R12).
__global__ __launch_bounds__(256) void k_scan3(const int* __restrict__ cnt,
                                               const int* __restrict__ boff,
                                               int* __restrict__ row_ptr,
                                               int* __restrict__ eidx, int n) {
    int b = blockIdx.x;
    int t = threadIdx.x;
    int lane = t & 63, w = t >> 6;
    int base = b * 1024 + t * 4;
    int orig[4], v[4];
    #pragma unroll
    for (int i = 0; i < 4; ++i) {
        orig[i] = (base + i < n) ? cnt[base + i] : 0;
        v[i] = (orig[i] + 3) & ~3;
    }
    int tsum = v[0] + v[1] + v[2] + v[3];
    int x = tsum;
    #pragma unroll
    for (int off = 1; off < 64; off <<= 1) {
        int tt = __shfl_up(x, off, 64);
        if (lane >= off) x += tt;
    }
    __shared__ int ws[4];
    if (lane == 63) ws[w] = x;
    __syncthreads();
    int woff = 0;
    for (int k = 0; k < 4; ++k) if (k < w) woff += ws[k];
    int excl = boff[b] + woff + x - tsum;
    #pragma unroll
    for (int i = 0; i < 4; ++i) {
        if (base + i < n) {
            row_ptr[base + i] = excl;
            for (int j = excl + orig[i]; j < excl + v[i]; ++j) eidx[j] = n;  // pad sentinel
        }
        excl += v[i];
    }
}

// atomic-free fill: slot = row_ptr[dst] + perm[e] (rank from k_count).
__global__ void k_fill(const int* __restrict__ ei, const int* __restrict__ row_ptr,
                       const int* __restrict__ perm, int* __restrict__ eidx, int E) {
    int e0 = (blockIdx.x * blockDim.x + threadIdx.x) * 4;
    if (e0 + 3 < E) {
        int4 s = *(const int4*)(ei + e0);
        int4 d = *(const int4*)(ei + E + e0);
        int4 pv = *(const int4*)(perm + e0);
        eidx[row_ptr[d.x] + pv.x] = s.x;
        eidx[row_ptr[d.y] + pv.y] = s.y;
        eidx[row_ptr[d.z] + pv.z] = s.z;
        eidx[row_ptr[d.w] + pv.w] = s.w;
    } else {
        for (int e = e0; e < E; ++e)
            eidx[row_ptr[ei[E + e]] + perm[e]] = ei[e];
    }
}

// zero sentinel rows. Stride trap (R10 bug): gathers read row N at N*stride
// for THEIR stride. xb: 128. bufB: 256. bufA read at 128-stride by the L4
// gather, but L2/L3 256-stride agg writes clobber N*128 -> re-zero (k_zeroA128)
// after L3's GEMM consumed bufA, before the L4 gather.
__global__ void k_zero(unsigned short* __restrict__ xb, unsigned short* __restrict__ bufA,
                       unsigned short* __restrict__ bufB, int N) {
    int t = threadIdx.x;   // 256
    if (t < 128) xb[(size_t)N * 128 + t] = 0;
    if (t < 128) bufA[(size_t)N * 128 + t] = 0;
    bufB[(size_t)N * 256 + t] = 0;
}

__global__ void k_zeroA128(unsigned short* __restrict__ bufA, int N) {
    int t = threadIdx.x;   // 128
    bufA[(size_t)N * 128 + t] = 0;
}

// S[n] = sum_e dinv[src]  (layer-invariant; pads hit dinv[N]=0)
__global__ __launch_bounds__(256) void k_ssum(const int* __restrict__ row_ptr,
                                              const int* __restrict__ eidx,
                                              const float* __restrict__ dinv,
                                              float* __restrict__ S, int N) {
    int n = blockIdx.x * 4 + (threadIdx.x >> 6);
    if (n >= N) return;
    int l = threadIdx.x & 63;
    int b = row_ptr[n], e = row_ptr[n + 1];
    float s = 0.f;
    for (int j = b + l * 4; j < e; j += 256) {
        int4 sv = *(const int4*)(eidx + j);
        s += (dinv[sv.x] + dinv[sv.y]) + (dinv[sv.z] + dinv[sv.w]);
    }
    #pragma unroll
    for (int off = 1; off < 64; off <<= 1) s += __shfl_xor(s, off, 64);
    if (l == 0) S[n] = s;
}

__global__ void k_init_affine(float* __restrict__ s, float* __restrict__ sh,
                              float* __restrict__ sums) {
    int c = threadIdx.x;
    s[c] = 1.0f;
    sh[c] = 0.0f;
    sums[c] = 0.f;
    sums[256 + c] = 0.f;
}

// ---------------- W prep ----------------
__global__ void k_prepW(const float* __restrict__ W, const float* __restrict__ scale,
                        unsigned short* __restrict__ Wt, int K, int DO) {
    int idx = blockIdx.x * blockDim.x + threadIdx.x;
    if (idx < K * DO) {
        int k = idx / DO, n = idx % DO;
        float v = W[idx];
        if (scale) v *= scale[k];
        Wt[(size_t)n * K + k] = f2bf(v);
    }
}

__global__ __launch_bounds__(256) void k_prepd(const float* __restrict__ W,
                                               const float* __restrict__ sh,
                                               float* __restrict__ d, int K, int DO) {
    int c = blockIdx.x;
    int t = threadIdx.x;
    float a = (t < K) ? sh[t] * W[(size_t)t * DO + c] : 0.f;
    #pragma unroll
    for (int off = 1; off < 64; off <<= 1) a += __shfl_xor(a, off, 64);
    __shared__ float ws[4];
    if ((t & 63) == 0) ws[t >> 6] = a;
    __syncthreads();
    if (t == 0) d[c] = ws[0] + ws[1] + ws[2] + ws[3];
}

// ---------------- wave-per-node aggregation: PURE SUM over prescaled rows ----
// Input rows are h_hat = dinv*h. conv = dn*(sum_e h_hat[src] + h_hat[n]); ws = dn*S[n]+dn^2
// non-EPI: o = s[c]*conv + sh[c]*ws       EPI: o = leaky(conv + ws*dv[c] + bias[c])
// (R8 lesson: keep VGPR <= ~40; unroll depth 4 only.)
template<int COLS, bool EPI>
__global__ __launch_bounds__(256) void k_aggw(const unsigned short* __restrict__ h,
    const float* __restrict__ s, const float* __restrict__ sh,
    const float* __restrict__ dv, const float* __restrict__ bias,
    const int* __restrict__ row_ptr, const int* __restrict__ eidx,
    const float* __restrict__ dinv, const float* __restrict__ S,
    unsigned short* __restrict__ t, int N) {
    constexpr int LPR = COLS / 8;
    constexpr int GR  = 64 / LPR;
    constexpr int SH  = (COLS == 256) ? 8 : 7;
    int n = blockIdx.x * 4 + (threadIdx.x >> 6);
    if (n >= N) return;
    int l = threadIdx.x & 63;
    int ct = l & (LPR - 1);
    int gp = l / LPR;
    const unsigned short* up = h + ct * 8;
    int b = row_ptr[n], e = row_ptr[n + 1];
    int cnt4 = e - b;                       // multiple of 4
    int per = (((cnt4 + GR - 1) / GR) + 3) & ~3;
    int jb = b + gp * per;
    int je = min(jb + per, e);
    float acc[8] = {};
    if (gp == 0) {                          // self term, weight 1 (already prescaled)
        short8 hv = *(const short8*)(up + ((size_t)n << SH));
        #pragma unroll
        for (int i = 0; i < 8; ++i) acc[i] += bf2f((unsigned short)hv[i]);
    }
    for (int j = jb; j < je; j += 4) {
        int4 sv = *(const int4*)(eidx + j);
        short8 r0 = *(const short8*)(up + ((size_t)sv.x << SH));
        short8 r1 = *(const short8*)(up + ((size_t)sv.y << SH));
        short8 r2 = *(const short8*)(up + ((size_t)sv.z << SH));
        short8 r3 = *(const short8*)(up + ((size_t)sv.w << SH));
        #pragma unroll
        for (int i = 0; i < 8; ++i) {
            float a01 = bf2f((unsigned short)r0[i]) + bf2f((unsigned short)r1[i]);
            float a23 = bf2f((unsigned short)r2[i]) + bf2f((unsigned short)r3[i]);
            acc[i] += a01 + a23;
        }
    }
    #pragma unroll
    for (int mask = LPR; mask < 64; mask <<= 1) {
        #pragma unroll
        for (int i = 0; i < 8; ++i) acc[i] += __shfl_xor(acc[i], mask, 64);
    }
    if (gp == 0) {
        float dn = dinv[n];
        float ws = dn * S[n] + dn * dn;
        short8 ov;
        #pragma unroll
        for (int i = 0; i < 8; ++i) {
            int col = ct * 8 + i;
            float o;
            if constexpr (EPI) {
                o = dn * acc[i] + ws * dv[col] + bias[col];
                o = o > 0.f ? o : NEG_SLOPE * o;
            } else {
                o = s[col] * (dn * acc[i]) + sh[col] * ws;
            }
            ov[i] = (short)f2bf(o);
        }
        *(short8*)(t + ((size_t)n << SH) + ct * 8) = ov;
    }
}

// ---------------- staged MFMA GEMM (128x128 tile, BK=64, swizzled LDS) -------
// FUSE: bias+leaky+BN-partials, store h_hat = bf16(dinv[row]*z) for next gather.
// !FUSE: store raw acc (L4: input already prescaled -> output is z_hat).
template<int K, int DO, bool FUSE>
__global__ __launch_bounds__(256) void k_mfma2(
    const unsigned short* __restrict__ A, const unsigned short* __restrict__ Wt,
    const float* __restrict__ bias, const float* __restrict__ dinv,
    unsigned short* __restrict__ H, float* __restrict__ sums, int M) {
    __shared__ unsigned short Asm[128 * 64];
    __shared__ unsigned short Bsm[128 * 64];
    __shared__ float ls[2][128];
    int tid = threadIdx.x;
    int l = tid & 63, w = tid >> 6;
    int wr = w & 1, wc = w >> 1;
    int rl = l & 15, kh = l >> 4;
    int Rb = blockIdx.x * 128;
    int Cb = blockIdx.y * 128;
    int srow = tid >> 3;
    int sd   = tid & 7;
    f32x4 acc[4][4] = {};
    for (int k0 = 0; k0 < K; k0 += 64) {
        #pragma unroll
        for (int i = 0; i < 4; ++i) {
            int row = i * 32 + srow;
            int ss = sd ^ (row & 7);
            int rg = Rb + row; if (rg >= M) rg = M - 1;
            gload_lds16(A + (size_t)rg * K + k0 + ss * 8,
                        (char*)Asm + i * 4096 + w * 1024);
            gload_lds16(Wt + (size_t)(Cb + row) * K + k0 + ss * 8,
                        (char*)Bsm + i * 4096 + w * 1024);
        }
        __syncthreads();
        #pragma unroll
        for (int kk = 0; kk < 2; ++kk) {
            short8 af[4], bf[4];
            #pragma unroll
            for (int mf = 0; mf < 4; ++mf) {
                int r = wr * 64 + mf * 16 + rl;
                int slot = (kk * 4 + kh) ^ (r & 7);
                af[mf] = *(const short8*)((const char*)Asm + r * 128 + slot * 16);
            }
            #pragma unroll
            for (int nf = 0; nf < 4; ++nf) {
                int c = wc * 64 + nf * 16 + rl;
                int slot = (kk * 4 + kh) ^ (c & 7);
                bf[nf] = *(const short8*)((const char*)Bsm + c * 128 + slot * 16);
            }
            #pragma unroll
            for (int mf = 0; mf < 4; ++mf)
                #pragma unroll
                for (int nf = 0; nf < 4; ++nf)
                    acc[mf][nf] = __builtin_amdgcn_mfma_f32_16x16x32_bf16(
                        af[mf], bf[nf], acc[mf][nf], 0, 0, 0);
        }
        __syncthreads();
    }
    if constexpr (FUSE) {
        for (int c = tid; c < 128; c += 256) { ls[0][c] = 0.f; ls[1][c] = 0.f; }
        __syncthreads();
        float p1[4] = {}, p2[4] = {};
        #pragma unroll
        for (int mf = 0; mf < 4; ++mf) {
            #pragma unroll
            for (int r = 0; r < 4; ++r) {
                int row = Rb + wr * 64 + mf * 16 + kh * 4 + r;
                if (row < M) {
                    float dr = dinv[row];
                    #pragma unroll
                    for (int nf = 0; nf < 4; ++nf) {
                        int col = Cb + wc * 64 + nf * 16 + rl;
                        float z = acc[mf][nf][r] + bias[col];
                        z = z > 0.f ? z : NEG_SLOPE * z;
                        H[(size_t)row * DO + col] = f2bf(dr * z);
                        p1[nf] += z; p2[nf] += z * z;
                    }
                }
            }
        }
        #pragma unroll
        for (int nf = 0; nf < 4; ++nf) {
            int cl = wc * 64 + nf * 16 + rl;
            atomicAdd(&ls[0][cl], p1[nf]);
            atomicAdd(&ls[1][cl], p2[nf]);
        }
        __syncthreads();
        for (int c = tid; c < 128; c += 256) {
            atomicAdd(&sums[Cb + c], ls[0][c]);
            atomicAdd(&sums[256 + Cb + c], ls[1][c]);
        }
    } else {
        #pragma unroll
        for (int nf = 0; nf < 4; ++nf) {
            int col = Cb + wc * 64 + nf * 16 + rl;
            #pragma unroll
            for (int mf = 0; mf < 4; ++mf) {
                #pragma unroll
                for (int r = 0; r < 4; ++r) {
                    int row = Rb + wr * 64 + mf * 16 + kh * 4 + r;
                    if (row < M) H[(size_t)row * DO + col] = f2bf(acc[mf][nf][r]);
                }
            }
        }
    }
}

// ---------------- BN finalize -> affine (re-zeroes sums) ----------------
__global__ void k_finalize(float* __restrict__ sums, const float* __restrict__ g,
                           const float* __restrict__ bt, float* __restrict__ s_out,
                           float* __restrict__ sh_out, float Nf) {
    int c = threadIdx.x;
    float mu = sums[c] / Nf;
    float var = sums[256 + c] / Nf - mu * mu;
    float rs = rsqrtf(var + BN_EPS);
    float sc = g[c] * rs;
    s_out[c] = sc;
    sh_out[c] = bt[c] - mu * sc;
    sums[c] = 0.f;
    sums[256 + c] = 0.f;
}

// ---------------- global mean pool, two-stage; pool1 fuses L4 BN stats ------
__global__ void k_pool1(const unsigned short* __restrict__ h, const int* __restrict__ batch,
                        float* __restrict__ part, float* __restrict__ sums, int N) {
    int g = blockIdx.x;
    int sidx = blockIdx.y;
    int c = threadIdx.x;   // 128
    int lo = 0, hi = N;
    while (lo < hi) { int m = (lo + hi) >> 1; if (batch[m] < g) lo = m + 1; else hi = m; }
    int start = lo; hi = N;
    while (lo < hi) { int m = (lo + hi) >> 1; if (batch[m] < g + 1) lo = m + 1; else hi = m; }
    int end = lo;
    float acc = 0.f, sq = 0.f;
    for (int r = start + sidx; r < end; r += POOL_S) {
        float v = bf2f(h[(size_t)r * 128 + c]);
        acc += v; sq += v * v;
    }
    part[((size_t)g * POOL_S + sidx) * 128 + c] = acc;
    atomicAdd(&sums[c], acc);
    atomicAdd(&sums[256 + c], sq);
}

__global__ void k_pool2(const float* __restrict__ part, const int* __restrict__ batch,
                        const float* __restrict__ s, const float* __restrict__ sh,
                        float* __restrict__ out, int N) {
    int g = blockIdx.x;
    int c = threadIdx.x;
    int lo = 0, hi = N;
    while (lo < hi) { int m = (lo + hi) >> 1; if (batch[m] < g) lo = m + 1; else hi = m; }
    int start = lo; hi = N;
    while (lo < hi) { int m = (lo + hi) >> 1; if (batch[m] < g + 1) lo = m + 1; else hi = m; }
    int cnt = lo - start;
    float acc = 0.f;
    #pragma unroll
    for (int i = 0; i < POOL_S; ++i) acc += part[((size_t)g * POOL_S + i) * 128 + c];
    out[(size_t)g * 128 + c] = (cnt > 0) ? (s[c] * acc / (float)cnt + sh[c]) : 0.f;
}

// ---------------- host ----------------

static inline size_t align256(size_t x) { return (x + 255) & ~(size_t)255; }

extern "C" void kernel_launch(void* const* d_in, const int* in_sizes, int n_in,
                              void* d_out, int out_size, void* d_ws, size_t ws_size,
                              hipStream_t stream) {
    const float* x   = (const float*)d_in[0];
    const int* ei    = (const int*)d_in[1];
    const int* batch = (const int*)d_in[2];
    const float* Wp[4]  = {(const float*)d_in[3], (const float*)d_in[7],
                           (const float*)d_in[11], (const float*)d_in[15]};
    const float* bp[4]  = {(const float*)d_in[4], (const float*)d_in[8],
                           (const float*)d_in[12], (const float*)d_in[16]};
    const float* gp[4]  = {(const float*)d_in[5], (const float*)d_in[9],
                           (const float*)d_in[13], (const float*)d_in[17]};
    const float* btp[4] = {(const float*)d_in[6], (const float*)d_in[10],
                           (const float*)d_in[14], (const float*)d_in[18]};

    const int N = in_sizes[0] / 128;
    const int E = in_sizes[1] / 2;
    const int G = out_size / 128;

    char* p = (char*)d_ws;
    int* deg_cnt = (int*)p;            p += align256((size_t)N * 4);
    int* row_ptr = (int*)p;            p += align256((size_t)(N + 1) * 4);
    float* dinv = (float*)p;           p += align256((size_t)(N + 1) * 4);
    float* Svec = (float*)p;           p += align256((size_t)N * 4);
    int* bsum = (int*)p;               p += align256(64 * 4);
    int* boff = (int*)p;               p += align256(64 * 4);
    int* perm = (int*)p;               p += align256((size_t)E * 4);
    int* eidx = (int*)p;               p += align256((size_t)(E + 3 * (N + 1)) * 4);
    float* sums = (float*)p;           p += align256(512 * 4);
    float* s_arr = (float*)p;          p += align256(5 * 256 * 4);
    float* sh_arr = (float*)p;         p += align256(5 * 256 * 4);
    float* dvec = (float*)p;           p += align256(256 * 4);
    unsigned short* Wt = (unsigned short*)p; p += align256(256 * 256 * 2);
    float* part = (float*)p;           p += align256((size_t)G * POOL_S * 128 * 4);
    unsigned short* xb = (unsigned short*)p;   p += align256((size_t)(N + 1) * 128 * 2);
    unsigned short* bufA = (unsigned short*)p; p += align256((size_t)(N + 1) * 256 * 2);
    unsigned short* bufB = (unsigned short*)p; p += align256((size_t)(N + 1) * 256 * 2);

    // ---- CSR (padded) + invariants ----
    hipMemsetAsync(deg_cnt, 0, (size_t)N * 4, stream);
    k_count<<<(E / 4 + 255) / 256, 256, 0, stream>>>(ei, deg_cnt, perm, E);
    const int nb = (N + 1023) / 1024;
    k_scan1<<<nb, 256, 0, stream>>>(deg_cnt, bsum, dinv, N);
    k_scan2<<<1, 64, 0, stream>>>(bsum, boff, row_ptr, nb, N);
    k_scan3<<<nb, 256, 0, stream>>>(deg_cnt, boff, row_ptr, eidx, N);
    k_fill<<<(E / 4 + 255) / 256, 256, 0, stream>>>(ei, row_ptr, perm, eidx, E);
    k_zero<<<1, 256, 0, stream>>>(xb, bufA, bufB, N);
    k_ssum<<<(N + 3) / 4, 256, 0, stream>>>(row_ptr, eidx, dinv, Svec, N);
    k_cvt<<<(N * 128 / 8 + 255) / 256, 256, 0, stream>>>(x, dinv, xb, N * 128 / 8);
    k_init_affine<<<1, 256, 0, stream>>>(s_arr, sh_arr, sums);

    const int ablocks = (N + 3) / 4;
    const int gx = (N + 127) / 128;

    // ---- L1: agg(xb_hat) [N,128] -> mfma 128->256 fused (writes h1_hat) ----
    k_aggw<128, false><<<ablocks, 256, 0, stream>>>(xb, s_arr, sh_arr, nullptr, nullptr,
        row_ptr, eidx, dinv, Svec, bufA, N);
    k_prepW<<<(128 * 256 + 255) / 256, 256, 0, stream>>>(Wp[0], nullptr, Wt, 128, 256);
    k_mfma2<128, 256, true><<<dim3(gx, 2), 256, 0, stream>>>(bufA, Wt, bp[0], dinv, bufB, sums, N);
    k_finalize<<<1, 256, 0, stream>>>(sums, gp[0], btp[0], s_arr + 256, sh_arr + 256, (float)N);

    // ---- L2, L3 ----
    for (int L = 1; L <= 2; ++L) {
        k_aggw<256, false><<<ablocks, 256, 0, stream>>>(bufB, s_arr + L * 256, sh_arr + L * 256,
            nullptr, nullptr, row_ptr, eidx, dinv, Svec, bufA, N);
        k_prepW<<<(256 * 256 + 255) / 256, 256, 0, stream>>>(Wp[L], nullptr, Wt, 256, 256);
        k_mfma2<256, 256, true><<<dim3(gx, 2), 256, 0, stream>>>(bufA, Wt, bp[L], dinv, bufB, sums, N);
        k_finalize<<<1, 256, 0, stream>>>(sums, gp[L], btp[L],
                                          s_arr + (L + 1) * 256, sh_arr + (L + 1) * 256, (float)N);
    }

    // ---- restore bufA's 128-stride sentinel row (clobbered by 256-stride writes) ----
    k_zeroA128<<<1, 128, 0, stream>>>(bufA, N);

    // ---- L4: GEMM-first on h3_hat (row scale commutes) -> z_hat; agg; pool ----
    k_prepW<<<(256 * 128 + 255) / 256, 256, 0, stream>>>(Wp[3], s_arr + 3 * 256, Wt, 256, 128);
    k_prepd<<<128, 256, 0, stream>>>(Wp[3], sh_arr + 3 * 256, dvec, 256, 128);
    k_mfma2<256, 128, false><<<dim3(gx, 1), 256, 0, stream>>>(bufB, Wt, nullptr, dinv, bufA, nullptr, N);
    k_aggw<128, true><<<ablocks, 256, 0, stream>>>(bufA, nullptr, nullptr, dvec, bp[3],
        row_ptr, eidx, dinv, Svec, bufB, N);
    dim3 pgrid(G, POOL_S);
    k_pool1<<<pgrid, 128, 0, stream>>>(bufB, batch, part, sums, N);
    k_finalize<<<1, 128, 0, stream>>>(sums, gp[3], btp[3], s_arr + 4 * 256, sh_arr + 4 * 256, (float)N);
    k_pool2<<<G, 128, 0, stream>>>(part, batch, s_arr + 4 * 256, sh_arr + 4 * 256,
                                   (float*)d_out, N);
}

// Round 14
// 445.783 us; speedup vs baseline: 1.7260x; 1.0096x over previous
//
#include <hip/hip_runtime.h>
#include <hip/hip_bf16.h>

#define NEG_SLOPE 0.01f
#define BN_EPS 1e-5f
#define POOL_S 16

typedef __attribute__((ext_vector_type(8))) short short8;
typedef __attribute__((ext_vector_type(4))) float f32x4;

__device__ __forceinline__ float bf2f(unsigned short b) {
    unsigned int u = ((unsigned int)b) << 16;
    float f; __builtin_memcpy(&f, &u, 4); return f;
}
__device__ __forceinline__ unsigned short f2bf(float f) {
    unsigned int u; __builtin_memcpy(&u, &f, 4);
    u = (u + 0x7FFFu + ((u >> 16) & 1u)) >> 16;
    return (unsigned short)u;
}

__device__ __forceinline__ void gload_lds16(const void* g, void* l) {
    __builtin_amdgcn_global_load_lds(
        (const __attribute__((address_space(1))) void*)g,
        (__attribute__((address_space(3))) void*)l, 16, 0, 0);
}

// ---------------- x fp32 -> bf16, prescaled by dinv[n] ----------------
__global__ void k_cvt(const float* __restrict__ x, const float* __restrict__ dinv,
                      unsigned short* __restrict__ xb, int total8) {
    int i = blockIdx.x * blockDim.x + threadIdx.x;
    if (i < total8) {
        float dn = dinv[i >> 4];
        float4 a = ((const float4*)x)[i * 2];
        float4 b = ((const float4*)x)[i * 2 + 1];
        short8 o;
        o[0] = (short)f2bf(dn * a.x); o[1] = (short)f2bf(dn * a.y);
        o[2] = (short)f2bf(dn * a.z); o[3] = (short)f2bf(dn * a.w);
        o[4] = (short)f2bf(dn * b.x); o[5] = (short)f2bf(dn * b.y);
        o[6] = (short)f2bf(dn * b.z); o[7] = (short)f2bf(dn * b.w);
        ((short8*)xb)[i] = o;
    }
}

// ---------------- CSR build ----------------
__global__ void k_count(const int* __restrict__ ei, int* __restrict__ cnt,
                        int* __restrict__ perm, int E) {
    int e0 = (blockIdx.x * blockDim.x + threadIdx.x) * 4;
    if (e0 + 3 < E) {
        int4 d = *(const int4*)(ei + E + e0);
        int4 pv;
        pv.x = atomicAdd(&cnt[d.x], 1);
        pv.y = atomicAdd(&cnt[d.y], 1);
        pv.z = atomicAdd(&cnt[d.z], 1);
        pv.w = atomicAdd(&cnt[d.w], 1);
        *(int4*)(perm + e0) = pv;
    } else {
        for (int e = e0; e < E; ++e) perm[e] = atomicAdd(&cnt[ei[E + e]], 1);
    }
}

__global__ __launch_bounds__(256) void k_scan1(const int* __restrict__ cnt,
                                               int* __restrict__ bsum,
                                               float* __restrict__ dinv, int n) {
    int b = blockIdx.x;
    int t = threadIdx.x;
    if (b == 0 && t == 0) dinv[n] = 0.f;    // sentinel zero weight
    int base = b * 1024 + t * 4;
    int s = 0;
    #pragma unroll
    for (int i = 0; i < 4; ++i) {
        if (base + i < n) {
            int v = cnt[base + i];
            dinv[base + i] = rsqrtf((float)(v + 1));
            s += (v + 3) & ~3;
        }
    }
    #pragma unroll
    for (int off = 1; off < 64; off <<= 1) s += __shfl_xor(s, off, 64);
    __shared__ int ws[4];
    if ((t & 63) == 0) ws[t >> 6] = s;
    __syncthreads();
    if (t == 0) bsum[b] = ws[0] + ws[1] + ws[2] + ws[3];
}

__global__ void k_scan2(const int* __restrict__ bsum, int* __restrict__ boff,
                        int* __restrict__ row_ptr, int nb, int n) {
    int lane = threadIdx.x;    // 64
    int v = (lane < nb) ? bsum[lane] : 0;
    int x = v;
    #pragma unroll
    for (int off = 1; off < 64; off <<= 1) {
        int t = __shfl_up(x, off, 64);
        if (lane >= off) x += t;
    }
    if (lane < nb) boff[lane] = x - v;
    if (lane == 63) row_ptr[n] = x;
}

// scan3: writes row_ptr AND the pad sentinels.
__global__ __launch_bounds__(256) void k_scan3(const int* __restrict__ cnt,
                                               const int* __restrict__ boff,
                                               int* __restrict__ row_ptr,
                                               int* __restrict__ eidx, int n) {
    int b = blockIdx.x;
    int t = threadIdx.x;
    int lane = t & 63, w = t >> 6;
    int base = b * 1024 + t * 4;
    int orig[4], v[4];
    #pragma unroll
    for (int i = 0; i < 4; ++i) {
        orig[i] = (base + i < n) ? cnt[base + i] : 0;
        v[i] = (orig[i] + 3) & ~3;
    }
    int tsum = v[0] + v[1] + v[2] + v[3];
    int x = tsum;
    #pragma unroll
    for (int off = 1; off < 64; off <<= 1) {
        int tt = __shfl_up(x, off, 64);
        if (lane >= off) x += tt;
    }
    __shared__ int ws[4];
    if (lane == 63) ws[w] = x;
    __syncthreads();
    int woff = 0;
    for (int k = 0; k < 4; ++k) if (k < w) woff += ws[k];
    int excl = boff[b] + woff + x - tsum;
    #pragma unroll
    for (int i = 0; i < 4; ++i) {
        if (base + i < n) {
            row_ptr[base + i] = excl;
            for (int j = excl + orig[i]; j < excl + v[i]; ++j) eidx[j] = n;
        }
        excl += v[i];
    }
}

// atomic-free fill: slot = row_ptr[dst] + perm[e].
__global__ void k_fill(const int* __restrict__ ei, const int* __restrict__ row_ptr,
                       const int* __restrict__ perm, int* __restrict__ eidx, int E) {
    int e0 = (blockIdx.x * blockDim.x + threadIdx.x) * 4;
    if (e0 + 3 < E) {
        int4 s = *(const int4*)(ei + e0);
        int4 d = *(const int4*)(ei + E + e0);
        int4 pv = *(const int4*)(perm + e0);
        eidx[row_ptr[d.x] + pv.x] = s.x;
        eidx[row_ptr[d.y] + pv.y] = s.y;
        eidx[row_ptr[d.z] + pv.z] = s.z;
        eidx[row_ptr[d.w] + pv.w] = s.w;
    } else {
        for (int e = e0; e < E; ++e)
            eidx[row_ptr[ei[E + e]] + perm[e]] = ei[e];
    }
}

// init affine + sums + sentinel rows (merged k_zero, R13).
// Stride trap (R10): bufA's 128-stride sentinel is re-zeroed in k_prepd
// (after L3's 256-stride writes clobber it, before the L4 gather).
__global__ void k_init(float* __restrict__ s, float* __restrict__ sh,
                       float* __restrict__ sums, unsigned short* __restrict__ xb,
                       unsigned short* __restrict__ bufA,
                       unsigned short* __restrict__ bufB, int N) {
    int c = threadIdx.x;   // 256
    s[c] = 1.0f;
    sh[c] = 0.0f;
    sums[c] = 0.f;
    sums[256 + c] = 0.f;
    if (c < 128) { xb[(size_t)N * 128 + c] = 0; bufA[(size_t)N * 128 + c] = 0; }
    bufB[(size_t)N * 256 + c] = 0;
}

// S[n] = sum_e dinv[src]  (layer-invariant; pads hit dinv[N]=0). 8 waves/block.
__global__ __launch_bounds__(512) void k_ssum(const int* __restrict__ row_ptr,
                                              const int* __restrict__ eidx,
                                              const float* __restrict__ dinv,
                                              float* __restrict__ S, int N) {
    int n = blockIdx.x * 8 + (threadIdx.x >> 6);
    if (n >= N) return;
    int l = threadIdx.x & 63;
    int b = row_ptr[n], e = row_ptr[n + 1];
    float s = 0.f;
    for (int j = b + l * 4; j < e; j += 256) {
        int4 sv = *(const int4*)(eidx + j);
        s += (dinv[sv.x] + dinv[sv.y]) + (dinv[sv.z] + dinv[sv.w]);
    }
    #pragma unroll
    for (int off = 1; off < 64; off <<= 1) s += __shfl_xor(s, off, 64);
    if (l == 0) S[n] = s;
}

// ---------------- W prep ----------------
__global__ void k_prepW(const float* __restrict__ W, const float* __restrict__ scale,
                        unsigned short* __restrict__ Wt, int K, int DO) {
    int idx = blockIdx.x * blockDim.x + threadIdx.x;
    if (idx < K * DO) {
        int k = idx / DO, n = idx % DO;
        float v = W[idx];
        if (scale) v *= scale[k];
        Wt[(size_t)n * K + k] = f2bf(v);
    }
}

// d[c] = sum_k sh[k]*W[k][c]; block 0 also restores bufA's 128-stride sentinel
// (safe: launched after L3's GEMM consumed bufA, before L4's gather).
__global__ __launch_bounds__(256) void k_prepd(const float* __restrict__ W,
                                               const float* __restrict__ sh,
                                               float* __restrict__ d,
                                               unsigned short* __restrict__ bufA,
                                               int K, int DO, int N) {
    int c = blockIdx.x;
    int t = threadIdx.x;
    if (c == 0 && t < 128) bufA[(size_t)N * 128 + t] = 0;
    float a = (t < K) ? sh[t] * W[(size_t)t * DO + c] : 0.f;
    #pragma unroll
    for (int off = 1; off < 64; off <<= 1) a += __shfl_xor(a, off, 64);
    __shared__ float ws[4];
    if ((t & 63) == 0) ws[t >> 6] = a;
    __syncthreads();
    if (t == 0) d[c] = ws[0] + ws[1] + ws[2] + ws[3];
}

// ---------------- wave-per-node aggregation: PURE SUM over prescaled rows ----
// 8 waves/block; idx-prefetch pipeline. (R8 lesson: keep VGPR low, rows
// unroll-4 only — unroll-8 at VGPR 60 serialized loads, 5x regression.)
template<int COLS, bool EPI>
__global__ __launch_bounds__(512) void k_aggw(const unsigned short* __restrict__ h,
    const float* __restrict__ s, const float* __restrict__ sh,
    const float* __restrict__ dv, const float* __restrict__ bias,
    const int* __restrict__ row_ptr, const int* __restrict__ eidx,
    const float* __restrict__ dinv, const float* __restrict__ S,
    unsigned short* __restrict__ t, int N) {
    constexpr int LPR = COLS / 8;
    constexpr int GR  = 64 / LPR;
    constexpr int SH  = (COLS == 256) ? 8 : 7;
    int n = blockIdx.x * 8 + (threadIdx.x >> 6);
    if (n >= N) return;
    int l = threadIdx.x & 63;
    int ct = l & (LPR - 1);
    int gp = l / LPR;
    const unsigned short* up = h + ct * 8;
    int b = row_ptr[n], e = row_ptr[n + 1];
    int cnt4 = e - b;                       // multiple of 4
    int per = (((cnt4 + GR - 1) / GR) + 3) & ~3;
    int jb = b + gp * per;
    int je = min(jb + per, e);
    float acc[8] = {};
    if (gp == 0) {                          // self term (prescaled, weight 1)
        short8 hv = *(const short8*)(up + ((size_t)n << SH));
        #pragma unroll
        for (int i = 0; i < 8; ++i) acc[i] += bf2f((unsigned short)hv[i]);
    }
    if (jb < je) {
        int4 sv = *(const int4*)(eidx + jb);      // prefetched indices
        for (int j = jb; j < je; ) {
            int4 cur = sv;
            j += 4;
            if (j < je) sv = *(const int4*)(eidx + j);
            short8 r0 = *(const short8*)(up + ((size_t)cur.x << SH));
            short8 r1 = *(const short8*)(up + ((size_t)cur.y << SH));
            short8 r2 = *(const short8*)(up + ((size_t)cur.z << SH));
            short8 r3 = *(const short8*)(up + ((size_t)cur.w << SH));
            #pragma unroll
            for (int i = 0; i < 8; ++i) {
                float a01 = bf2f((unsigned short)r0[i]) + bf2f((unsigned short)r1[i]);
                float a23 = bf2f((unsigned short)r2[i]) + bf2f((unsigned short)r3[i]);
                acc[i] += a01 + a23;
            }
        }
    }
    #pragma unroll
    for (int mask = LPR; mask < 64; mask <<= 1) {
        #pragma unroll
        for (int i = 0; i < 8; ++i) acc[i] += __shfl_xor(acc[i], mask, 64);
    }
    if (gp == 0) {
        float dn = dinv[n];
        float ws = dn * S[n] + dn * dn;
        short8 ov;
        #pragma unroll
        for (int i = 0; i < 8; ++i) {
            int col = ct * 8 + i;
            float o;
            if constexpr (EPI) {
                o = dn * acc[i] + ws * dv[col] + bias[col];
                o = o > 0.f ? o : NEG_SLOPE * o;
            } else {
                o = s[col] * (dn * acc[i]) + sh[col] * ws;
            }
            ov[i] = (short)f2bf(o);
        }
        *(short8*)(t + ((size_t)n << SH) + ct * 8) = ov;
    }
}

// ---------------- staged MFMA GEMM (128x128 tile, BK=64, swizzled LDS) -------
template<int K, int DO, bool FUSE>
__global__ __launch_bounds__(256) void k_mfma2(
    const unsigned short* __restrict__ A, const unsigned short* __restrict__ Wt,
    const float* __restrict__ bias, const float* __restrict__ dinv,
    unsigned short* __restrict__ H, float* __restrict__ sums, int M) {
    __shared__ unsigned short Asm[128 * 64];
    __shared__ unsigned short Bsm[128 * 64];
    __shared__ float ls[2][128];
    int tid = threadIdx.x;
    int l = tid & 63, w = tid >> 6;
    int wr = w & 1, wc = w >> 1;
    int rl = l & 15, kh = l >> 4;
    int Rb = blockIdx.x * 128;
    int Cb = blockIdx.y * 128;
    int srow = tid >> 3;
    int sd   = tid & 7;
    f32x4 acc[4][4] = {};
    for (int k0 = 0; k0 < K; k0 += 64) {
        #pragma unroll
        for (int i = 0; i < 4; ++i) {
            int row = i * 32 + srow;
            int ss = sd ^ (row & 7);
            int rg = Rb + row; if (rg >= M) rg = M - 1;
            gload_lds16(A + (size_t)rg * K + k0 + ss * 8,
                        (char*)Asm + i * 4096 + w * 1024);
            gload_lds16(Wt + (size_t)(Cb + row) * K + k0 + ss * 8,
                        (char*)Bsm + i * 4096 + w * 1024);
        }
        __syncthreads();
        #pragma unroll
        for (int kk = 0; kk < 2; ++kk) {
            short8 af[4], bf[4];
            #pragma unroll
            for (int mf = 0; mf < 4; ++mf) {
                int r = wr * 64 + mf * 16 + rl;
                int slot = (kk * 4 + kh) ^ (r & 7);
                af[mf] = *(const short8*)((const char*)Asm + r * 128 + slot * 16);
            }
            #pragma unroll
            for (int nf = 0; nf < 4; ++nf) {
                int c = wc * 64 + nf * 16 + rl;
                int slot = (kk * 4 + kh) ^ (c & 7);
                bf[nf] = *(const short8*)((const char*)Bsm + c * 128 + slot * 16);
            }
            #pragma unroll
            for (int mf = 0; mf < 4; ++mf)
                #pragma unroll
                for (int nf = 0; nf < 4; ++nf)
                    acc[mf][nf] = __builtin_amdgcn_mfma_f32_16x16x32_bf16(
                        af[mf], bf[nf], acc[mf][nf], 0, 0, 0);
        }
        __syncthreads();
    }
    if constexpr (FUSE) {
        for (int c = tid; c < 128; c += 256) { ls[0][c] = 0.f; ls[1][c] = 0.f; }
        __syncthreads();
        float p1[4] = {}, p2[4] = {};
        #pragma unroll
        for (int mf = 0; mf < 4; ++mf) {
            #pragma unroll
            for (int r = 0; r < 4; ++r) {
                int row = Rb + wr * 64 + mf * 16 + kh * 4 + r;
                if (row < M) {
                    float dr = dinv[row];
                    #pragma unroll
                    for (int nf = 0; nf < 4; ++nf) {
                        int col = Cb + wc * 64 + nf * 16 + rl;
                        float z = acc[mf][nf][r] + bias[col];
                        z = z > 0.f ? z : NEG_SLOPE * z;
                        H[(size_t)row * DO + col] = f2bf(dr * z);
                        p1[nf] += z; p2[nf] += z * z;
                    }
                }
            }
        }
        #pragma unroll
        for (int nf = 0; nf < 4; ++nf) {
            int cl = wc * 64 + nf * 16 + rl;
            atomicAdd(&ls[0][cl], p1[nf]);
            atomicAdd(&ls[1][cl], p2[nf]);
        }
        __syncthreads();
        for (int c = tid; c < 128; c += 256) {
            atomicAdd(&sums[Cb + c], ls[0][c]);
            atomicAdd(&sums[256 + Cb + c], ls[1][c]);
        }
    } else {
        #pragma unroll
        for (int nf = 0; nf < 4; ++nf) {
            int col = Cb + wc * 64 + nf * 16 + rl;
            #pragma unroll
            for (int mf = 0; mf < 4; ++mf) {
                #pragma unroll
                for (int r = 0; r < 4; ++r) {
                    int row = Rb + wr * 64 + mf * 16 + kh * 4 + r;
                    if (row < M) H[(size_t)row * DO + col] = f2bf(acc[mf][nf][r]);
                }
            }
        }
    }
}

// ---------------- BN finalize -> affine (re-zeroes sums) ----------------
__global__ void k_finalize(float* __restrict__ sums, const float* __restrict__ g,
                           const float* __restrict__ bt, float* __restrict__ s_out,
                           float* __restrict__ sh_out, float Nf) {
    int c = threadIdx.x;
    float mu = sums[c] / Nf;
    float var = sums[256 + c] / Nf - mu * mu;
    float rs = rsqrtf(var + BN_EPS);
    float sc = g[c] * rs;
    s_out[c] = sc;
    sh_out[c] = bt[c] - mu * sc;
    sums[c] = 0.f;
    sums[256 + c] = 0.f;
}

// ---------------- global mean pool, two-stage; pool1 fuses L4 BN stats ------
__global__ void k_pool1(const unsigned short* __restrict__ h, const int* __restrict__ batch,
                        float* __restrict__ part, float* __restrict__ sums, int N) {
    int g = blockIdx.x;
    int sidx = blockIdx.y;
    int c = threadIdx.x;   // 128
    int lo = 0, hi = N;
    while (lo < hi) { int m = (lo + hi) >> 1; if (batch[m] < g) lo = m + 1; else hi = m; }
    int start = lo; hi = N;
    while (lo < hi) { int m = (lo + hi) >> 1; if (batch[m] < g + 1) lo = m + 1; else hi = m; }
    int end = lo;
    float acc = 0.f, sq = 0.f;
    for (int r = start + sidx; r < end; r += POOL_S) {
        float v = bf2f(h[(size_t)r * 128 + c]);
        acc += v; sq += v * v;
    }
    part[((size_t)g * POOL_S + sidx) * 128 + c] = acc;
    atomicAdd(&sums[c], acc);
    atomicAdd(&sums[256 + c], sq);
}

__global__ void k_pool2(const float* __restrict__ part, const int* __restrict__ batch,
                        const float* __restrict__ s, const float* __restrict__ sh,
                        float* __restrict__ out, int N) {
    int g = blockIdx.x;
    int c = threadIdx.x;
    int lo = 0, hi = N;
    while (lo < hi) { int m = (lo + hi) >> 1; if (batch[m] < g) lo = m + 1; else hi = m; }
    int start = lo; hi = N;
    while (lo < hi) { int m = (lo + hi) >> 1; if (batch[m] < g + 1) lo = m + 1; else hi = m; }
    int cnt = lo - start;
    float acc = 0.f;
    #pragma unroll
    for (int i = 0; i < POOL_S; ++i) acc += part[((size_t)g * POOL_S + i) * 128 + c];
    out[(size_t)g * 128 + c] = (cnt > 0) ? (s[c] * acc / (float)cnt + sh[c]) : 0.f;
}

// ---------------- host ----------------

static inline size_t align256(size_t x) { return (x + 255) & ~(size_t)255; }

extern "C" void kernel_launch(void* const* d_in, const int* in_sizes, int n_in,
                              void* d_out, int out_size, void* d_ws, size_t ws_size,
                              hipStream_t stream) {
    const float* x   = (const float*)d_in[0];
    const int* ei    = (const int*)d_in[1];
    const int* batch = (const int*)d_in[2];
    const float* Wp[4]  = {(const float*)d_in[3], (const float*)d_in[7],
                           (const float*)d_in[11], (const float*)d_in[15]};
    const float* bp[4]  = {(const float*)d_in[4], (const float*)d_in[8],
                           (const float*)d_in[12], (const float*)d_in[16]};
    const float* gp[4]  = {(const float*)d_in[5], (const float*)d_in[9],
                           (const float*)d_in[13], (const float*)d_in[17]};
    const float* btp[4] = {(const float*)d_in[6], (const float*)d_in[10],
                           (const float*)d_in[14], (const float*)d_in[18]};

    const int N = in_sizes[0] / 128;
    const int E = in_sizes[1] / 2;
    const int G = out_size / 128;

    char* p = (char*)d_ws;
    int* deg_cnt = (int*)p;            p += align256((size_t)N * 4);
    int* row_ptr = (int*)p;            p += align256((size_t)(N + 1) * 4);
    float* dinv = (float*)p;           p += align256((size_t)(N + 1) * 4);
    float* Svec = (float*)p;           p += align256((size_t)N * 4);
    int* bsum = (int*)p;               p += align256(64 * 4);
    int* boff = (int*)p;               p += align256(64 * 4);
    int* perm = (int*)p;               p += align256((size_t)E * 4);
    int* eidx = (int*)p;               p += align256((size_t)(E + 3 * (N + 1)) * 4);
    float* sums = (float*)p;           p += align256(512 * 4);
    float* s_arr = (float*)p;          p += align256(5 * 256 * 4);
    float* sh_arr = (float*)p;         p += align256(5 * 256 * 4);
    float* dvec = (float*)p;           p += align256(256 * 4);
    unsigned short* Wt = (unsigned short*)p; p += align256(256 * 256 * 2);
    float* part = (float*)p;           p += align256((size_t)G * POOL_S * 128 * 4);
    unsigned short* xb = (unsigned short*)p;   p += align256((size_t)(N + 1) * 128 * 2);
    unsigned short* bufA = (unsigned short*)p; p += align256((size_t)(N + 1) * 256 * 2);
    unsigned short* bufB = (unsigned short*)p; p += align256((size_t)(N + 1) * 256 * 2);

    // ---- CSR (padded) + invariants ----
    hipMemsetAsync(deg_cnt, 0, (size_t)N * 4, stream);
    k_count<<<(E / 4 + 255) / 256, 256, 0, stream>>>(ei, deg_cnt, perm, E);
    const int nb = (N + 1023) / 1024;
    k_scan1<<<nb, 256, 0, stream>>>(deg_cnt, bsum, dinv, N);
    k_scan2<<<1, 64, 0, stream>>>(bsum, boff, row_ptr, nb, N);
    k_scan3<<<nb, 256, 0, stream>>>(deg_cnt, boff, row_ptr, eidx, N);
    k_fill<<<(E / 4 + 255) / 256, 256, 0, stream>>>(ei, row_ptr, perm, eidx, E);
    k_init<<<1, 256, 0, stream>>>(s_arr, sh_arr, sums, xb, bufA, bufB, N);
    k_ssum<<<(N + 7) / 8, 512, 0, stream>>>(row_ptr, eidx, dinv, Svec, N);
    k_cvt<<<(N * 128 / 8 + 255) / 256, 256, 0, stream>>>(x, dinv, xb, N * 128 / 8);

    const int ablocks = (N + 7) / 8;
    const int gx = (N + 127) / 128;

    // ---- L1: agg(xb_hat) [N,128] -> mfma 128->256 fused (writes h1_hat) ----
    k_aggw<128, false><<<ablocks, 512, 0, stream>>>(xb, s_arr, sh_arr, nullptr, nullptr,
        row_ptr, eidx, dinv, Svec, bufA, N);
    k_prepW<<<(128 * 256 + 255) / 256, 256, 0, stream>>>(Wp[0], nullptr, Wt, 128, 256);
    k_mfma2<128, 256, true><<<dim3(gx, 2), 256, 0, stream>>>(bufA, Wt, bp[0], dinv, bufB, sums, N);
    k_finalize<<<1, 256, 0, stream>>>(sums, gp[0], btp[0], s_arr + 256, sh_arr + 256, (float)N);

    // ---- L2, L3 ----
    for (int L = 1; L <= 2; ++L) {
        k_aggw<256, false><<<ablocks, 512, 0, stream>>>(bufB, s_arr + L * 256, sh_arr + L * 256,
            nullptr, nullptr, row_ptr, eidx, dinv, Svec, bufA, N);
        k_prepW<<<(256 * 256 + 255) / 256, 256, 0, stream>>>(Wp[L], nullptr, Wt, 256, 256);
        k_mfma2<256, 256, true><<<dim3(gx, 2), 256, 0, stream>>>(bufA, Wt, bp[L], dinv, bufB, sums, N);
        k_finalize<<<1, 256, 0, stream>>>(sums, gp[L], btp[L],
                                          s_arr + (L + 1) * 256, sh_arr + (L + 1) * 256, (float)N);
    }

    // ---- L4: GEMM-first on h3_hat -> z_hat; agg; pool. prepd block 0 also
    // restores bufA's 128-stride sentinel (stream-ordered after L3 GEMM). ----
    k_prepW<<<(256 * 128 + 255) / 256, 256, 0, stream>>>(Wp[3], s_arr + 3 * 256, Wt, 256, 128);
    k_prepd<<<128, 256, 0, stream>>>(Wp[3], sh_arr + 3 * 256, dvec, bufA, 256, 128, N);
    k_mfma2<256, 128, false><<<dim3(gx, 1), 256, 0, stream>>>(bufB, Wt, nullptr, dinv, bufA, nullptr, N);
    k_aggw<128, true><<<ablocks, 512, 0, stream>>>(bufA, nullptr, nullptr, dvec, bp[3],
        row_ptr, eidx, dinv, Svec, bufB, N);
    dim3 pgrid(G, POOL_S);
    k_pool1<<<pgrid, 128, 0, stream>>>(bufB, batch, part, sums, N);
    k_finalize<<<1, 128, 0, stream>>>(sums, gp[3], btp[3], s_arr + 4 * 256, sh_arr + 4 * 256, (float)N);
    k_pool2<<<G, 128, 0, stream>>>(part, batch, s_arr + 4 * 256, sh_arr + 4 * 256,
                                   (float*)d_out, N);
}